// Round 12
// baseline (479.163 us; speedup 1.0000x reference)
//
#include <hip/hip_runtime.h>
#include <hip/hip_bf16.h>
#include <math.h>

#define D_MODEL 1024
#define D_FF    4096
#define NE      8
#define MT      256   // list alignment / gemm1 M tile

typedef __bf16 bf16x8 __attribute__((ext_vector_type(8)));
typedef float  f32x4  __attribute__((ext_vector_type(4)));

__device__ __forceinline__ void async16(const void* g, void* l) {
    __builtin_amdgcn_global_load_lds(
        (__attribute__((address_space(1))) uint32_t*)g,
        (__attribute__((address_space(3))) uint32_t*)l, 16, 0, 0);
}

// 128k x 128n transpose+cvt tile, reg-staged: src[K][N] f32 -> dst[N][K] bf16.
// 16 float4/thread issued upfront (outstanding bytes no longer LDS-capped);
// transpose via 4 sub-rounds through a 17KB [32][132] slice.
// Read-phase banks: (4*(kh+i)+f0)%32 — even/odd lane pairs alias 2-way (free, m136).
__device__ __forceinline__ void transpose_cvt_tile128(
    const float* __restrict__ s, __bf16* __restrict__ d,
    int K, int N, int kt, int nt, int tid, float (*sl)[132])
{
    int rbase = tid >> 5;          // 0..7
    int c0 = (tid & 31) * 4;       // 0..124: 32 thr x float4 = 512B/row
    float4 v[16];
#pragma unroll
    for (int j = 0; j < 16; ++j)
        v[j] = *reinterpret_cast<const float4*>(
            s + (size_t)(kt + rbase + 8 * j) * N + nt + c0);

    int f0 = tid >> 1;             // 0..127
    int kh = (tid & 1) * 16;
#pragma unroll
    for (int s4 = 0; s4 < 4; ++s4) {
        if (s4) __syncthreads();   // guard slice reuse
#pragma unroll
        for (int jj = 0; jj < 4; ++jj)
            *reinterpret_cast<float4*>(&sl[rbase + 8 * jj][c0]) = v[4 * s4 + jj];
        __syncthreads();
        bf16x8 p0, p1;
#pragma unroll
        for (int i = 0; i < 8; ++i) p0[i] = (__bf16)sl[kh + i][f0];
#pragma unroll
        for (int i = 0; i < 8; ++i) p1[i] = (__bf16)sl[kh + 8 + i][f0];
        __bf16* dp = d + (size_t)(nt + f0) * K + kt + s4 * 32 + kh;
        *reinterpret_cast<bf16x8*>(dp) = p0;       // 32B k-contig store
        *reinterpret_cast<bf16x8*>(dp + 8) = p1;
    }
}

// -------- fused: router (bid<nrouter) | T(W1) | T(W2) | T(W3), 2048 tiles each --------
__global__ __launch_bounds__(256) void fused_pre(
    const float* __restrict__ x, const float* __restrict__ Wg,
    const float* __restrict__ bg, int* __restrict__ topidx,
    float* __restrict__ topw, __bf16* __restrict__ Xb,
    const float* __restrict__ W1, const float* __restrict__ W2,
    const float* __restrict__ W3,
    __bf16* __restrict__ W1t, __bf16* __restrict__ W2t,
    __bf16* __restrict__ W3t, int nrouter)
{
    __shared__ float sl[32][132];   // 16.9KB exchange slice (also router scratch)
    int bid = blockIdx.x, tid = threadIdx.x;

    if (bid >= nrouter) {
        int tt = bid - nrouter;       // 0..6143
        int m = tt >> 11;             // 0=W1, 1=W2, 2=W3
        int r = tt & 2047;
        int e = r >> 8, rem = r & 255;
        if (m < 2) {                  // [K=1024][N=4096] per expert: 8 x 32 tiles
            const float* s = (m == 0) ? W1 : W2;
            __bf16*      d = (m == 0) ? W1t : W2t;
            int kt_i = rem >> 5, nt_i = rem & 31;
            transpose_cvt_tile128(s + ((size_t)e << 22), d + ((size_t)e << 22),
                                  D_MODEL, D_FF, kt_i * 128, nt_i * 128, tid, sl);
        } else {                      // W3 [K=4096][N=1024]: 32 x 8 tiles
            int kt_i = rem >> 3, nt_i = rem & 7;
            transpose_cvt_tile128(W3 + ((size_t)e << 22), W3t + ((size_t)e << 22),
                                  D_FF, D_MODEL, kt_i * 128, nt_i * 128, tid, sl);
        }
        return;
    }

    int n = bid;
    const float* xr = x + (size_t)n * D_MODEL;
    int d0 = tid * 4;
    float4 xv = *reinterpret_cast<const float4*>(xr + d0);

    union { __bf16 h[4]; ushort4 u; } pk;
    pk.h[0] = (__bf16)xv.x; pk.h[1] = (__bf16)xv.y;
    pk.h[2] = (__bf16)xv.z; pk.h[3] = (__bf16)xv.w;
    *reinterpret_cast<ushort4*>(Xb + (size_t)n * D_MODEL + d0) = pk.u;

    float part[NE];
#pragma unroll
    for (int e = 0; e < NE; ++e) part[e] = 0.f;
    float xs[4] = {xv.x, xv.y, xv.z, xv.w};
#pragma unroll
    for (int j = 0; j < 4; ++j) {
        const float4* wr = reinterpret_cast<const float4*>(Wg + (size_t)(d0 + j) * NE);
        float4 w0 = wr[0], w1 = wr[1];
        part[0] += xs[j] * w0.x; part[1] += xs[j] * w0.y;
        part[2] += xs[j] * w0.z; part[3] += xs[j] * w0.w;
        part[4] += xs[j] * w1.x; part[5] += xs[j] * w1.y;
        part[6] += xs[j] * w1.z; part[7] += xs[j] * w1.w;
    }
#pragma unroll
    for (int off = 32; off > 0; off >>= 1) {
#pragma unroll
        for (int e = 0; e < NE; ++e) part[e] += __shfl_down(part[e], off);
    }
    float* sred = &sl[0][0];
    float* slog = &sl[1][0];
    int wave = tid >> 6, lane = tid & 63;
    if (lane == 0) {
#pragma unroll
        for (int e = 0; e < NE; ++e) sred[wave * NE + e] = part[e];
    }
    __syncthreads();
    if (tid < NE)
        slog[tid] = bg[tid] + sred[tid] + sred[NE + tid] + sred[2 * NE + tid] + sred[3 * NE + tid];
    __syncthreads();
    if (tid == 0) {
        float m0 = -1e30f, m1 = -1e30f; int i0 = 0, i1 = 0;
        for (int e = 0; e < NE; ++e) {
            float l = slog[e];
            if (l > m0)      { m1 = m0; i1 = i0; m0 = l; i0 = e; }
            else if (l > m1) { m1 = l;  i1 = e; }
        }
        float w1 = expf(m1 - m0);
        float s  = 1.f + w1;
        topidx[n * 2 + 0] = i0; topidx[n * 2 + 1] = i1;
        topw[n * 2 + 0] = 1.f / s; topw[n * 2 + 1] = w1 / s;
    }
}

// ---------------- build per-expert padded row lists (align 256) + pairRow ----------------
__global__ __launch_bounds__(256) void build_lists_kernel(
    const int* __restrict__ topidx, const float* __restrict__ topw,
    int* __restrict__ pairTok, float* __restrict__ pairW,
    int* __restrict__ rbe, int* __restrict__ pairRow,
    int npairs, int maxrows, int maxblk)
{
    __shared__ int cnt[NE], cur[NE], pof[NE];
    int tid = threadIdx.x;
    if (tid < NE) { cnt[tid] = 0; cur[tid] = 0; }
    for (int i = tid; i < maxrows; i += 256) pairTok[i] = -1;
    for (int i = tid; i < maxblk; i += 256) rbe[i] = -1;
    __syncthreads();
    for (int p = tid; p < npairs; p += 256) atomicAdd(&cnt[topidx[p]], 1);
    __syncthreads();
    if (tid == 0) {
        int off = 0;
        for (int e = 0; e < NE; ++e) { pof[e] = off; off += (cnt[e] + MT - 1) & ~(MT - 1); }
        for (int e = 0; e < NE; ++e) {
            int nb = (cnt[e] + MT - 1) / MT;
            for (int j = 0; j < nb; ++j) rbe[pof[e] / MT + j] = e;
        }
    }
    __syncthreads();
    for (int p = tid; p < npairs; p += 256) {
        int e = topidx[p];
        int pos = atomicAdd(&cur[e], 1);
        int r = pof[e] + pos;
        pairTok[r]  = p >> 1;
        pairW[r]    = topw[p];
        pairRow[p]  = r;
    }
}

// ---- GEMM1: 256x128 dual-B, 4-region half-tile pipeline (R11, measured ~= R7) ----
__global__ __launch_bounds__(512) void gemm1_mfma(
    const __bf16* __restrict__ Xb, const __bf16* __restrict__ W1t,
    const __bf16* __restrict__ W2t, const float* __restrict__ b1,
    const float* __restrict__ b2, const int* __restrict__ pairTok,
    const int* __restrict__ rbe, const __bf16* __restrict__ zpg,
    __bf16* __restrict__ hidden)
{
    int b = blockIdx.x;
    int e = rbe[b];
    if (e < 0) return;
    int fblk = blockIdx.y * 128;

    __shared__ __bf16 smem[4][16384];   // 4 regions x 32KB

    int tid = threadIdx.x, w = tid >> 6, l = tid & 63;
    int ss4 = (l & 3) ^ ((l >> 3) & 3);   // write slot permutation
    int r0 = b * MT;

    const __bf16* aptr[2];
#pragma unroll
    for (int j = 0; j < 2; ++j) {
        int row = w * 32 + j * 16 + (l >> 2);
        int tok = pairTok[r0 + row];
        aptr[j] = (tok >= 0 ? Xb + (size_t)tok * D_MODEL : zpg) + ss4 * 8;
    }
    int wrow = fblk + w * 16 + (l >> 2);
    const __bf16* b1ptr = W1t + ((size_t)e << 22) + (size_t)wrow * D_MODEL + ss4 * 8;
    const __bf16* b2ptr = W2t + ((size_t)e << 22) + (size_t)wrow * D_MODEL + ss4 * 8;

    int wm = (w >> 1) * 64, wf = (w & 1) * 64;
    int lm = l & 15;
    int sl = (((l >> 4) ^ ((lm >> 1) & 3)) << 3);   // read slot (row>>1)&3 = (lm>>1)&3

    f32x4 c1[4][4], c2[4][4];
#pragma unroll
    for (int mi = 0; mi < 4; ++mi)
#pragma unroll
        for (int fj = 0; fj < 4; ++fj) {
            c1[mi][fj] = (f32x4){0.f, 0.f, 0.f, 0.f};
            c2[mi][fj] = (f32x4){0.f, 0.f, 0.f, 0.f};
        }

    auto stage = [&](int reg, int k0) {   // 4 async16 per thread per half-tile
        __bf16* base = &smem[reg][0];
        async16(aptr[0] + k0, base + w * 1024 + l * 8);
        async16(aptr[1] + k0, base + w * 1024 + 512 + l * 8);
        async16(b1ptr + k0, base + 8192 + w * 512 + l * 8);
        async16(b2ptr + k0, base + 12288 + w * 512 + l * 8);
    };

    const int NH = D_MODEL / 32;   // 32 half-steps
    stage(0, 0);
    stage(1, 32);
    stage(2, 64);
    asm volatile("s_waitcnt vmcnt(8)" ::: "memory");   // half 0 landed; 1,2 in flight
    __builtin_amdgcn_s_barrier();

    for (int s = 0; s < NH; ++s) {
        const __bf16* sb = &smem[s & 3][0];
        bf16x8 a[4], bv[4];
#pragma unroll
        for (int mi = 0; mi < 4; ++mi)
            a[mi] = *reinterpret_cast<const bf16x8*>(sb + (wm + mi * 16 + lm) * 32 + sl);
#pragma unroll
        for (int fj = 0; fj < 4; ++fj)
            bv[fj] = *reinterpret_cast<const bf16x8*>(sb + 8192 + (wf + fj * 16 + lm) * 32 + sl);
        if (s + 3 < NH) stage((s + 3) & 3, (s + 3) * 32);   // distributed stage-issue
        __builtin_amdgcn_s_setprio(1);
#pragma unroll
        for (int fj = 0; fj < 4; ++fj)
#pragma unroll
            for (int mi = 0; mi < 4; ++mi)
                c1[mi][fj] = __builtin_amdgcn_mfma_f32_16x16x32_bf16(a[mi], bv[fj], c1[mi][fj], 0, 0, 0);
        __builtin_amdgcn_s_setprio(0);
        __builtin_amdgcn_s_barrier();
#pragma unroll
        for (int fj = 0; fj < 4; ++fj)
            bv[fj] = *reinterpret_cast<const bf16x8*>(sb + 12288 + (wf + fj * 16 + lm) * 32 + sl);
        __builtin_amdgcn_s_setprio(1);
#pragma unroll
        for (int fj = 0; fj < 4; ++fj)
#pragma unroll
            for (int mi = 0; mi < 4; ++mi)
                c2[mi][fj] = __builtin_amdgcn_mfma_f32_16x16x32_bf16(a[mi], bv[fj], c2[mi][fj], 0, 0, 0);
        __builtin_amdgcn_s_setprio(0);
        if (s + 3 < NH)      asm volatile("s_waitcnt vmcnt(8)" ::: "memory");
        else if (s + 2 < NH) asm volatile("s_waitcnt vmcnt(4)" ::: "memory");
        else if (s + 1 < NH) asm volatile("s_waitcnt vmcnt(0)" ::: "memory");
        __builtin_amdgcn_s_barrier();
    }

#pragma unroll
    for (int fj = 0; fj < 4; ++fj) {
        int f = fblk + wf + fj * 16 + lm;
        float b1v = b1[e * D_FF + f];
        float b2v = b2[e * D_FF + f];
#pragma unroll
        for (int mi = 0; mi < 4; ++mi)
#pragma unroll
            for (int r = 0; r < 4; ++r) {
                int m = wm + mi * 16 + (l >> 4) * 4 + r;
                float h1 = c1[mi][fj][r] + b1v;
                float h2 = c2[mi][fj][r] + b2v;
                float g = 0.5f * h1 * (1.f + erff(h1 * 0.70710678118654752f));
                hidden[(size_t)(r0 + m) * D_FF + f] = (__bf16)(g * h2);
            }
    }
}

// ---------------- GEMM2: 128x128, BK=64, K=4096, po-store (no atomics) ----------------
__global__ __launch_bounds__(512, 4) void gemm2_mfma(
    const __bf16* __restrict__ hidden, const __bf16* __restrict__ W3t,
    const float* __restrict__ b3, const int* __restrict__ rbe,
    float* __restrict__ po)
{
    int rb = blockIdx.x;           // 128-row block
    int e = rbe[rb >> 1];
    if (e < 0) return;
    int dblk = blockIdx.y * 128;

    __shared__ __bf16 smem[2][16384];

    int tid = threadIdx.x, w = tid >> 6, l = tid & 63;
    int ss8 = (l & 7) ^ (l >> 3);
    int r0m = rb * 128;

    const __bf16* abase = hidden + (size_t)(r0m + w * 16 + (l >> 3)) * D_FF + ss8 * 8;
    const __bf16* bbase = W3t + ((size_t)e << 22)
        + (size_t)(dblk + w * 16 + (l >> 3)) * D_FF + ss8 * 8;

    int wm = (w >> 1) * 32, wn = (w & 1) * 64;
    int lm = l & 15;

    f32x4 c[2][4];
#pragma unroll
    for (int mi = 0; mi < 2; ++mi)
#pragma unroll
        for (int nj = 0; nj < 4; ++nj) c[mi][nj] = (f32x4){0.f, 0.f, 0.f, 0.f};

    auto stage = [&](int buf, int k0) {
        __bf16* base = &smem[buf][0];
        async16(abase + k0,              base + w * 1024 + l * 8);
        async16(abase + 8 * D_FF + k0,   base + w * 1024 + 512 + l * 8);
        async16(bbase + k0,              base + 8192 + w * 1024 + l * 8);
        async16(bbase + 8 * D_FF + k0,   base + 8192 + w * 1024 + 512 + l * 8);
    };

    stage(0, 0);
    __syncthreads();
    const int NT = D_FF / 64;   // 64
    for (int t = 0; t < NT; ++t) {
        int cur = t & 1;
        if (t + 1 < NT) stage(cur ^ 1, (t + 1) * 64);
        const __bf16* sb = &smem[cur][0];
#pragma unroll
        for (int ks = 0; ks < 2; ++ks) {
            int sl = (((ks * 4 + (l >> 4)) ^ (l & 7)) << 3);
            bf16x8 a[2];
#pragma unroll
            for (int mi = 0; mi < 2; ++mi)
                a[mi] = *reinterpret_cast<const bf16x8*>(sb + (wm + mi * 16 + lm) * 64 + sl);
#pragma unroll
            for (int nj = 0; nj < 4; ++nj) {
                bf16x8 bv = *reinterpret_cast<const bf16x8*>(sb + 8192 + (wn + nj * 16 + lm) * 64 + sl);
#pragma unroll
                for (int mi = 0; mi < 2; ++mi)
                    c[mi][nj] = __builtin_amdgcn_mfma_f32_16x16x32_bf16(a[mi], bv, c[mi][nj], 0, 0, 0);
            }
        }
        __syncthreads();
    }

#pragma unroll
    for (int nj = 0; nj < 4; ++nj) {
        int d = dblk + wn + nj * 16 + lm;
        float b3v = b3[e * D_MODEL + d];
#pragma unroll
        for (int mi = 0; mi < 2; ++mi)
#pragma unroll
            for (int r = 0; r < 4; ++r) {
                int m = wm + mi * 16 + (l >> 4) * 4 + r;
                po[(size_t)(r0m + m) * D_MODEL + d] = c[mi][nj][r] + b3v;
            }
    }
}

// ---------------- combine: out[t] = w0*po[r0] + w1*po[r1] ----------------
__global__ __launch_bounds__(256) void combine_kernel(
    const float* __restrict__ po, const float* __restrict__ topw,
    const int* __restrict__ pairRow, float* __restrict__ out)
{
    int t = blockIdx.x, tid = threadIdx.x;
    int d = tid * 4;
    float w0 = topw[t * 2], w1 = topw[t * 2 + 1];
    int r0 = pairRow[t * 2], r1 = pairRow[t * 2 + 1];
    float4 v0 = *reinterpret_cast<const float4*>(po + (size_t)r0 * D_MODEL + d);
    float4 v1 = *reinterpret_cast<const float4*>(po + (size_t)r1 * D_MODEL + d);
    float4 o;
    o.x = w0 * v0.x + w1 * v1.x;
    o.y = w0 * v0.y + w1 * v1.y;
    o.z = w0 * v0.z + w1 * v1.z;
    o.w = w0 * v0.w + w1 * v1.w;
    *reinterpret_cast<float4*>(out + (size_t)t * D_MODEL + d) = o;
}

extern "C" void kernel_launch(void* const* d_in, const int* in_sizes, int n_in,
                              void* d_out, int out_size, void* d_ws, size_t ws_size,
                              hipStream_t stream)
{
    const float* x  = (const float*)d_in[0];
    const float* Wg = (const float*)d_in[1];
    const float* bg = (const float*)d_in[2];
    const float* W1 = (const float*)d_in[3];
    const float* b1 = (const float*)d_in[4];
    const float* W2 = (const float*)d_in[5];
    const float* b2 = (const float*)d_in[6];
    const float* W3 = (const float*)d_in[7];
    const float* b3 = (const float*)d_in[8];
    float* out = (float*)d_out;

    int N = in_sizes[0] / D_MODEL;     // 2048
    int npairs = N * 2;
    int maxblk = npairs / MT + NE;     // 24
    int maxrows = maxblk * MT;         // 6144

    char* ws = (char*)d_ws;
    size_t off = 0;
    auto alloc = [&](size_t bytes) -> void* {
        void* p = ws + off;
        off = (off + bytes + 255) & ~(size_t)255;
        return p;
    };
    int*    topidx  = (int*)   alloc((size_t)npairs * 4);
    float*  topw    = (float*) alloc((size_t)npairs * 4);
    int*    pairTok = (int*)   alloc((size_t)maxrows * 4);
    float*  pairW   = (float*) alloc((size_t)maxrows * 4);
    int*    rbe     = (int*)   alloc((size_t)maxblk * 4);
    int*    pairRow = (int*)   alloc((size_t)npairs * 4);
    __bf16* Xb      = (__bf16*)alloc((size_t)N * D_MODEL * 2);
    __bf16* hidden  = (__bf16*)alloc((size_t)maxrows * D_FF * 2);
    __bf16* zpg     = (__bf16*)alloc(4096);
    const size_t WSZ = (size_t)NE * D_MODEL * D_FF * 2;   // 64 MB per matrix
    __bf16* W1t = (__bf16*)alloc(WSZ);
    __bf16* W2t = (__bf16*)alloc(WSZ);
    __bf16* W3t = (__bf16*)alloc(WSZ);
    float*  po  = (float*)W1t;   // overlay: W1t dead after gemm1 (25MB < 64MB)
    (void)ws_size; (void)n_in; (void)pairW;

    hipMemsetAsync(zpg, 0, 4096, stream);

    // router + T(W1) + T(W2) + T(W3): 2048 reg-staged 128x128 tiles per matrix
    fused_pre<<<N + 3 * 2048, 256, 0, stream>>>(
        x, Wg, bg, topidx, topw, Xb, W1, W2, W3, W1t, W2t, W3t, N);
    build_lists_kernel<<<1, 256, 0, stream>>>(topidx, topw, pairTok, pairW, rbe,
                                              pairRow, npairs, maxrows, maxblk);
    gemm1_mfma<<<dim3(maxblk, D_FF / 128), 512, 0, stream>>>(
        Xb, W1t, W2t, b1, b2, pairTok, rbe, zpg, hidden);
    gemm2_mfma<<<dim3(maxblk * 2, D_MODEL / 128), 512, 0, stream>>>(
        hidden, W3t, b3, rbe, po);
    combine_kernel<<<N, 256, 0, stream>>>(po, topw, pairRow, out);
}

// Round 13
// 332.910 us; speedup vs baseline: 1.4393x; 1.4393x over previous
//
#include <hip/hip_runtime.h>
#include <hip/hip_bf16.h>
#include <math.h>

#define D_MODEL 1024
#define D_FF    4096
#define NE      8
#define MT      256   // list alignment / gemm1 M tile

typedef __bf16 bf16x8 __attribute__((ext_vector_type(8)));
typedef float  f32x4  __attribute__((ext_vector_type(4)));

__device__ __forceinline__ void async16(const void* g, void* l) {
    __builtin_amdgcn_global_load_lds(
        (__attribute__((address_space(1))) uint32_t*)g,
        (__attribute__((address_space(3))) uint32_t*)l, 16, 0, 0);
}

// bijective XCD chunking (m204): contiguous runs of nwg/8 blocks per XCD
__device__ __forceinline__ int xcd_swizzle(int lin, int nwg) {
    if ((nwg & 7) != 0) return lin;
    int q = nwg >> 3;
    return (lin & 7) * q + (lin >> 3);
}

// 128k x 64f transpose+cvt tile: src[K][N] f32 -> dst[N][K] bf16. (R9-verified)
__device__ __forceinline__ void transpose_tile_k128(
    const float* __restrict__ s, __bf16* __restrict__ d,
    int K, int N, int kt, int nt, int tid, float (*tile)[65])
{
    int tr = tid >> 4, tc = (tid & 15) * 4;
#pragma unroll
    for (int p = 0; p < 8; ++p) {
        float4 v = *reinterpret_cast<const float4*>(
            s + (size_t)(kt + tr + p * 16) * N + nt + tc);
        tile[tr + p * 16][tc + 0] = v.x;
        tile[tr + p * 16][tc + 1] = v.y;
        tile[tr + p * 16][tc + 2] = v.z;
        tile[tr + p * 16][tc + 3] = v.w;
    }
    __syncthreads();
    int kq = (tid & 15) * 8;
#pragma unroll
    for (int p = 0; p < 4; ++p) {
        int rr = (tid >> 4) + p * 16;   // f within tile
        bf16x8 pk;
#pragma unroll
        for (int i = 0; i < 8; ++i) pk[i] = (__bf16)tile[kq + i][rr];
        *reinterpret_cast<bf16x8*>(d + (size_t)(nt + rr) * K + kt + kq) = pk;
    }
}

// -------- fused: router (bid<nrouter) | T(W1) | T(W2) | T(W3) (R9-exact) --------
__global__ __launch_bounds__(256) void fused_pre(
    const float* __restrict__ x, const float* __restrict__ Wg,
    const float* __restrict__ bg, int* __restrict__ topidx,
    float* __restrict__ topw, __bf16* __restrict__ Xb,
    const float* __restrict__ W1, const float* __restrict__ W2,
    const float* __restrict__ W3,
    __bf16* __restrict__ W1t, __bf16* __restrict__ W2t,
    __bf16* __restrict__ W3t, int nrouter)
{
    __shared__ float buf[128][65];
    int bid = blockIdx.x, tid = threadIdx.x;

    if (bid >= nrouter) {
        int tt = bid - nrouter;
        if (tt < 2 * 4096) {            // W1/W2: [K=1024][N=4096] per expert
            const float* s = W1; __bf16* d = W1t;
            if (tt >= 4096) { s = W2; d = W2t; tt -= 4096; }
            int e = tt >> 9, rem = tt & 511;
            int kt_i = rem >> 6, nt_i = rem & 63;   // 8 ktiles x 64 ntiles
            transpose_tile_k128(s + ((size_t)e << 22), d + ((size_t)e << 22),
                                D_MODEL, D_FF, kt_i * 128, nt_i * 64, tid, buf);
        } else {                        // W3: [K=4096][N=1024] per expert
            tt -= 2 * 4096;
            int e = tt >> 9, rem = tt & 511;
            int kt_i = rem >> 4, nt_i = rem & 15;   // 32 ktiles x 16 ntiles
            transpose_tile_k128(W3 + ((size_t)e << 22), W3t + ((size_t)e << 22),
                                D_FF, D_MODEL, kt_i * 128, nt_i * 64, tid, buf);
        }
        return;
    }

    int n = bid;
    const float* xr = x + (size_t)n * D_MODEL;
    int d0 = tid * 4;
    float4 xv = *reinterpret_cast<const float4*>(xr + d0);

    union { __bf16 h[4]; ushort4 u; } pk;
    pk.h[0] = (__bf16)xv.x; pk.h[1] = (__bf16)xv.y;
    pk.h[2] = (__bf16)xv.z; pk.h[3] = (__bf16)xv.w;
    *reinterpret_cast<ushort4*>(Xb + (size_t)n * D_MODEL + d0) = pk.u;

    float part[NE];
#pragma unroll
    for (int e = 0; e < NE; ++e) part[e] = 0.f;
    float xs[4] = {xv.x, xv.y, xv.z, xv.w};
#pragma unroll
    for (int j = 0; j < 4; ++j) {
        const float4* wr = reinterpret_cast<const float4*>(Wg + (size_t)(d0 + j) * NE);
        float4 w0 = wr[0], w1 = wr[1];
        part[0] += xs[j] * w0.x; part[1] += xs[j] * w0.y;
        part[2] += xs[j] * w0.z; part[3] += xs[j] * w0.w;
        part[4] += xs[j] * w1.x; part[5] += xs[j] * w1.y;
        part[6] += xs[j] * w1.z; part[7] += xs[j] * w1.w;
    }
#pragma unroll
    for (int off = 32; off > 0; off >>= 1) {
#pragma unroll
        for (int e = 0; e < NE; ++e) part[e] += __shfl_down(part[e], off);
    }
    float* sred = &buf[0][0];
    float* slog = &buf[1][0];
    int wave = tid >> 6, lane = tid & 63;
    if (lane == 0) {
#pragma unroll
        for (int e = 0; e < NE; ++e) sred[wave * NE + e] = part[e];
    }
    __syncthreads();
    if (tid < NE)
        slog[tid] = bg[tid] + sred[tid] + sred[NE + tid] + sred[2 * NE + tid] + sred[3 * NE + tid];
    __syncthreads();
    if (tid == 0) {
        float m0 = -1e30f, m1 = -1e30f; int i0 = 0, i1 = 0;
        for (int e = 0; e < NE; ++e) {
            float l = slog[e];
            if (l > m0)      { m1 = m0; i1 = i0; m0 = l; i0 = e; }
            else if (l > m1) { m1 = l;  i1 = e; }
        }
        float w1 = expf(m1 - m0);
        float s  = 1.f + w1;
        topidx[n * 2 + 0] = i0; topidx[n * 2 + 1] = i1;
        topw[n * 2 + 0] = 1.f / s; topw[n * 2 + 1] = w1 / s;
    }
}

// ---------------- build per-expert padded row lists (align 256) + pairRow ----------------
__global__ __launch_bounds__(256) void build_lists_kernel(
    const int* __restrict__ topidx, const float* __restrict__ topw,
    int* __restrict__ pairTok, float* __restrict__ pairW,
    int* __restrict__ rbe, int* __restrict__ pairRow,
    int npairs, int maxrows, int maxblk)
{
    __shared__ int cnt[NE], cur[NE], pof[NE];
    int tid = threadIdx.x;
    if (tid < NE) { cnt[tid] = 0; cur[tid] = 0; }
    for (int i = tid; i < maxrows; i += 256) pairTok[i] = -1;
    for (int i = tid; i < maxblk; i += 256) rbe[i] = -1;
    __syncthreads();
    for (int p = tid; p < npairs; p += 256) atomicAdd(&cnt[topidx[p]], 1);
    __syncthreads();
    if (tid == 0) {
        int off = 0;
        for (int e = 0; e < NE; ++e) { pof[e] = off; off += (cnt[e] + MT - 1) & ~(MT - 1); }
        for (int e = 0; e < NE; ++e) {
            int nb = (cnt[e] + MT - 1) / MT;
            for (int j = 0; j < nb; ++j) rbe[pof[e] / MT + j] = e;
        }
    }
    __syncthreads();
    for (int p = tid; p < npairs; p += 256) {
        int e = topidx[p];
        int pos = atomicAdd(&cur[e], 1);
        int r = pof[e] + pos;
        pairTok[r]  = p >> 1;
        pairW[r]    = topw[p];
        pairRow[p]  = r;
    }
}

// ---- GEMM1: 256x128 dual-B, BK=64, 8 waves (R9-exact body) + XCD swizzle ----
// 1D grid 768 = maxblk x 32 fblks; consecutive wgids share fblk -> per-XCD
// 96-run working set = 8 experts x 2 x 256KB = 4MB = one XCD L2.
// R8 lesson: acc=128 regs, no min-waves launch_bounds.
__global__ __launch_bounds__(512) void gemm1_mfma(
    const __bf16* __restrict__ Xb, const __bf16* __restrict__ W1t,
    const __bf16* __restrict__ W2t, const float* __restrict__ b1,
    const float* __restrict__ b2, const int* __restrict__ pairTok,
    const int* __restrict__ rbe, const __bf16* __restrict__ zpg,
    __bf16* __restrict__ hidden, int maxblk)
{
    int wgid = xcd_swizzle(blockIdx.x, gridDim.x);
    int b = wgid % maxblk;
    int e = rbe[b];
    if (e < 0) return;
    int fblk = (wgid / maxblk) * 128;

    __shared__ __bf16 smem[2][32768];

    int tid = threadIdx.x, w = tid >> 6, l = tid & 63;
    int srcslot = (l & 7) ^ (l >> 3);   // LDS[row][s] = src[row][s ^ (row&7)]
    int r0 = b * MT;

    const __bf16* aptr[4];
#pragma unroll
    for (int j = 0; j < 4; ++j) {
        int row = w * 32 + j * 8 + (l >> 3);
        int tok = pairTok[r0 + row];
        aptr[j] = (tok >= 0 ? Xb + (size_t)tok * D_MODEL : zpg) + srcslot * 8;
    }
    const __bf16* b1base = W1t + ((size_t)e << 22)
        + (size_t)(fblk + w * 16 + (l >> 3)) * D_MODEL + srcslot * 8;
    const __bf16* b2base = W2t + ((size_t)e << 22)
        + (size_t)(fblk + w * 16 + (l >> 3)) * D_MODEL + srcslot * 8;

    int wm = (w >> 1) * 64, wf = (w & 1) * 64;
    int lm = l & 15;

    f32x4 c1[4][4], c2[4][4];
#pragma unroll
    for (int mi = 0; mi < 4; ++mi)
#pragma unroll
        for (int fj = 0; fj < 4; ++fj) {
            c1[mi][fj] = (f32x4){0.f, 0.f, 0.f, 0.f};
            c2[mi][fj] = (f32x4){0.f, 0.f, 0.f, 0.f};
        }

    auto stage = [&](int buf, int k0) {
        __bf16* base = &smem[buf][0];
#pragma unroll
        for (int j = 0; j < 4; ++j)
            async16(aptr[j] + k0, base + w * 2048 + j * 512);
        async16(b1base + k0,               base + 16384 + w * 1024);
        async16(b1base + 8 * D_MODEL + k0, base + 16384 + w * 1024 + 512);
        async16(b2base + k0,               base + 24576 + w * 1024);
        async16(b2base + 8 * D_MODEL + k0, base + 24576 + w * 1024 + 512);
    };

    stage(0, 0);
    __syncthreads();
    const int NT = D_MODEL / 64;   // 16
    for (int t = 0; t < NT; ++t) {
        int cur = t & 1;
        if (t + 1 < NT) stage(cur ^ 1, (t + 1) * 64);
        const __bf16* sb = &smem[cur][0];
#pragma unroll
        for (int ks = 0; ks < 2; ++ks) {
            int sl = (((ks * 4 + (l >> 4)) ^ (l & 7)) << 3);   // read XOR = row&7
            bf16x8 a[4];
#pragma unroll
            for (int mi = 0; mi < 4; ++mi)
                a[mi] = *reinterpret_cast<const bf16x8*>(sb + (wm + mi * 16 + lm) * 64 + sl);
#pragma unroll
            for (int fj = 0; fj < 4; ++fj) {
                int frow = wf + fj * 16 + lm;
                bf16x8 bv1 = *reinterpret_cast<const bf16x8*>(sb + 16384 + frow * 64 + sl);
                bf16x8 bv2 = *reinterpret_cast<const bf16x8*>(sb + 24576 + frow * 64 + sl);
#pragma unroll
                for (int mi = 0; mi < 4; ++mi) {
                    c1[mi][fj] = __builtin_amdgcn_mfma_f32_16x16x32_bf16(a[mi], bv1, c1[mi][fj], 0, 0, 0);
                    c2[mi][fj] = __builtin_amdgcn_mfma_f32_16x16x32_bf16(a[mi], bv2, c2[mi][fj], 0, 0, 0);
                }
            }
        }
        __syncthreads();
    }

#pragma unroll
    for (int fj = 0; fj < 4; ++fj) {
        int f = fblk + wf + fj * 16 + lm;
        float b1v = b1[e * D_FF + f];
        float b2v = b2[e * D_FF + f];
#pragma unroll
        for (int mi = 0; mi < 4; ++mi)
#pragma unroll
            for (int r = 0; r < 4; ++r) {
                int m = wm + mi * 16 + (l >> 4) * 4 + r;
                float h1 = c1[mi][fj][r] + b1v;
                float h2 = c2[mi][fj][r] + b2v;
                float g = 0.5f * h1 * (1.f + erff(h1 * 0.70710678118654752f));
                hidden[(size_t)(r0 + m) * D_FF + f] = (__bf16)(g * h2);
            }
    }
}

// ---------------- GEMM2: 128x128, BK=64, K=4096, po-store + XCD swizzle ----------------
__global__ __launch_bounds__(512, 4) void gemm2_mfma(
    const __bf16* __restrict__ hidden, const __bf16* __restrict__ W3t,
    const float* __restrict__ b3, const int* __restrict__ rbe,
    float* __restrict__ po, int nrb)
{
    int wgid = xcd_swizzle(blockIdx.x, gridDim.x);
    int rb = wgid % nrb;           // 128-row block
    int e = rbe[rb >> 1];
    if (e < 0) return;
    int dblk = (wgid / nrb) * 128;

    __shared__ __bf16 smem[2][16384];

    int tid = threadIdx.x, w = tid >> 6, l = tid & 63;
    int ss8 = (l & 7) ^ (l >> 3);
    int r0m = rb * 128;

    const __bf16* abase = hidden + (size_t)(r0m + w * 16 + (l >> 3)) * D_FF + ss8 * 8;
    const __bf16* bbase = W3t + ((size_t)e << 22)
        + (size_t)(dblk + w * 16 + (l >> 3)) * D_FF + ss8 * 8;

    int wm = (w >> 1) * 32, wn = (w & 1) * 64;
    int lm = l & 15;

    f32x4 c[2][4];
#pragma unroll
    for (int mi = 0; mi < 2; ++mi)
#pragma unroll
        for (int nj = 0; nj < 4; ++nj) c[mi][nj] = (f32x4){0.f, 0.f, 0.f, 0.f};

    auto stage = [&](int buf, int k0) {
        __bf16* base = &smem[buf][0];
        async16(abase + k0,              base + w * 1024 + l * 8);
        async16(abase + 8 * D_FF + k0,   base + w * 1024 + 512 + l * 8);
        async16(bbase + k0,              base + 8192 + w * 1024 + l * 8);
        async16(bbase + 8 * D_FF + k0,   base + 8192 + w * 1024 + 512 + l * 8);
    };

    stage(0, 0);
    __syncthreads();
    const int NT = D_FF / 64;   // 64
    for (int t = 0; t < NT; ++t) {
        int cur = t & 1;
        if (t + 1 < NT) stage(cur ^ 1, (t + 1) * 64);
        const __bf16* sb = &smem[cur][0];
#pragma unroll
        for (int ks = 0; ks < 2; ++ks) {
            int sl = (((ks * 4 + (l >> 4)) ^ (l & 7)) << 3);
            bf16x8 a[2];
#pragma unroll
            for (int mi = 0; mi < 2; ++mi)
                a[mi] = *reinterpret_cast<const bf16x8*>(sb + (wm + mi * 16 + lm) * 64 + sl);
#pragma unroll
            for (int nj = 0; nj < 4; ++nj) {
                bf16x8 bv = *reinterpret_cast<const bf16x8*>(sb + 8192 + (wn + nj * 16 + lm) * 64 + sl);
#pragma unroll
                for (int mi = 0; mi < 2; ++mi)
                    c[mi][nj] = __builtin_amdgcn_mfma_f32_16x16x32_bf16(a[mi], bv, c[mi][nj], 0, 0, 0);
            }
        }
        __syncthreads();
    }

#pragma unroll
    for (int nj = 0; nj < 4; ++nj) {
        int d = dblk + wn + nj * 16 + lm;
        float b3v = b3[e * D_MODEL + d];
#pragma unroll
        for (int mi = 0; mi < 2; ++mi)
#pragma unroll
            for (int r = 0; r < 4; ++r) {
                int m = wm + mi * 16 + (l >> 4) * 4 + r;
                po[(size_t)(r0m + m) * D_MODEL + d] = c[mi][nj][r] + b3v;
            }
    }
}

// ---------------- combine: out[t] = w0*po[r0] + w1*po[r1] ----------------
__global__ __launch_bounds__(256) void combine_kernel(
    const float* __restrict__ po, const float* __restrict__ topw,
    const int* __restrict__ pairRow, float* __restrict__ out)
{
    int t = blockIdx.x, tid = threadIdx.x;
    int d = tid * 4;
    float w0 = topw[t * 2], w1 = topw[t * 2 + 1];
    int r0 = pairRow[t * 2], r1 = pairRow[t * 2 + 1];
    float4 v0 = *reinterpret_cast<const float4*>(po + (size_t)r0 * D_MODEL + d);
    float4 v1 = *reinterpret_cast<const float4*>(po + (size_t)r1 * D_MODEL + d);
    float4 o;
    o.x = w0 * v0.x + w1 * v1.x;
    o.y = w0 * v0.y + w1 * v1.y;
    o.z = w0 * v0.z + w1 * v1.z;
    o.w = w0 * v0.w + w1 * v1.w;
    *reinterpret_cast<float4*>(out + (size_t)t * D_MODEL + d) = o;
}

extern "C" void kernel_launch(void* const* d_in, const int* in_sizes, int n_in,
                              void* d_out, int out_size, void* d_ws, size_t ws_size,
                              hipStream_t stream)
{
    const float* x  = (const float*)d_in[0];
    const float* Wg = (const float*)d_in[1];
    const float* bg = (const float*)d_in[2];
    const float* W1 = (const float*)d_in[3];
    const float* b1 = (const float*)d_in[4];
    const float* W2 = (const float*)d_in[5];
    const float* b2 = (const float*)d_in[6];
    const float* W3 = (const float*)d_in[7];
    const float* b3 = (const float*)d_in[8];
    float* out = (float*)d_out;

    int N = in_sizes[0] / D_MODEL;     // 2048
    int npairs = N * 2;
    int maxblk = npairs / MT + NE;     // 24
    int maxrows = maxblk * MT;         // 6144

    char* ws = (char*)d_ws;
    size_t off = 0;
    auto alloc = [&](size_t bytes) -> void* {
        void* p = ws + off;
        off = (off + bytes + 255) & ~(size_t)255;
        return p;
    };
    int*    topidx  = (int*)   alloc((size_t)npairs * 4);
    float*  topw    = (float*) alloc((size_t)npairs * 4);
    int*    pairTok = (int*)   alloc((size_t)maxrows * 4);
    float*  pairW   = (float*) alloc((size_t)maxrows * 4);
    int*    rbe     = (int*)   alloc((size_t)maxblk * 4);
    int*    pairRow = (int*)   alloc((size_t)npairs * 4);
    __bf16* Xb      = (__bf16*)alloc((size_t)N * D_MODEL * 2);
    __bf16* hidden  = (__bf16*)alloc((size_t)maxrows * D_FF * 2);
    __bf16* zpg     = (__bf16*)alloc(4096);
    const size_t WSZ = (size_t)NE * D_MODEL * D_FF * 2;   // 64 MB per matrix
    __bf16* W1t = (__bf16*)alloc(WSZ);
    __bf16* W2t = (__bf16*)alloc(WSZ);
    __bf16* W3t = (__bf16*)alloc(WSZ);
    float*  po  = (float*)W1t;   // overlay: W1t dead after gemm1 (25MB < 64MB)
    (void)ws_size; (void)n_in; (void)pairW;

    hipMemsetAsync(zpg, 0, 4096, stream);

    // router + T(W1) + T(W2) + T(W3): one BW-bound pass (R9-proven)
    fused_pre<<<N + 3 * 4096, 256, 0, stream>>>(
        x, Wg, bg, topidx, topw, Xb, W1, W2, W3, W1t, W2t, W3t, N);
    build_lists_kernel<<<1, 256, 0, stream>>>(topidx, topw, pairTok, pairW, rbe,
                                              pairRow, npairs, maxrows, maxblk);
    gemm1_mfma<<<maxblk * (D_FF / 128), 512, 0, stream>>>(
        Xb, W1t, W2t, b1, b2, pairTok, rbe, zpg, hidden, maxblk);
    gemm2_mfma<<<(maxblk * 2) * (D_MODEL / 128), 512, 0, stream>>>(
        hidden, W3t, b3, rbe, po, maxblk * 2);
    combine_kernel<<<N, 256, 0, stream>>>(po, topw, pairRow, out);
}

// Round 14
// 328.495 us; speedup vs baseline: 1.4587x; 1.0134x over previous
//
#include <hip/hip_runtime.h>
#include <hip/hip_bf16.h>
#include <math.h>

#define D_MODEL 1024
#define D_FF    4096
#define NE      8
#define MT      256   // list alignment / gemm1 M tile
#define NW3T    4096  // W3 transpose tiles: 8e x 32kt x 16nt (128k x 64f)

typedef __bf16 bf16x8 __attribute__((ext_vector_type(8)));
typedef float  f32x4  __attribute__((ext_vector_type(4)));

__device__ __forceinline__ void async16(const void* g, void* l) {
    __builtin_amdgcn_global_load_lds(
        (__attribute__((address_space(1))) uint32_t*)g,
        (__attribute__((address_space(3))) uint32_t*)l, 16, 0, 0);
}

// bijective XCD chunking (m204): contiguous runs of nwg/8 blocks per XCD
__device__ __forceinline__ int xcd_swizzle(int lin, int nwg) {
    if ((nwg & 7) != 0) return lin;
    int q = nwg >> 3;
    return (lin & 7) * q + (lin >> 3);
}

// 128k x 64f transpose+cvt tile: src[K][N] f32 -> dst[N][K] bf16. (R9-verified)
// 256 threads; caller may run two instances side-by-side (subgroups execute
// identical control flow, so the joint __syncthreads align).
__device__ __forceinline__ void transpose_tile_k128(
    const float* __restrict__ s, __bf16* __restrict__ d,
    int K, int N, int kt, int nt, int tid, float (*tile)[65])
{
    int tr = tid >> 4, tc = (tid & 15) * 4;
#pragma unroll
    for (int p = 0; p < 8; ++p) {
        float4 v = *reinterpret_cast<const float4*>(
            s + (size_t)(kt + tr + p * 16) * N + nt + tc);
        tile[tr + p * 16][tc + 0] = v.x;
        tile[tr + p * 16][tc + 1] = v.y;
        tile[tr + p * 16][tc + 2] = v.z;
        tile[tr + p * 16][tc + 3] = v.w;
    }
    __syncthreads();
    int kq = (tid & 15) * 8;
#pragma unroll
    for (int p = 0; p < 4; ++p) {
        int rr = (tid >> 4) + p * 16;   // f within tile
        bf16x8 pk;
#pragma unroll
        for (int i = 0; i < 8; ++i) pk[i] = (__bf16)tile[kq + i][rr];
        *reinterpret_cast<bf16x8*>(d + (size_t)(nt + rr) * K + kt + kq) = pk;
    }
}

// -------- fused: router (bid<nrouter) | T(W1) | T(W2)  (W3 moved into gemm1) --------
__global__ __launch_bounds__(256) void fused_pre(
    const float* __restrict__ x, const float* __restrict__ Wg,
    const float* __restrict__ bg, int* __restrict__ topidx,
    float* __restrict__ topw, __bf16* __restrict__ Xb,
    const float* __restrict__ W1, const float* __restrict__ W2,
    __bf16* __restrict__ W1t, __bf16* __restrict__ W2t, int nrouter)
{
    __shared__ float buf[128][65];
    int bid = blockIdx.x, tid = threadIdx.x;

    if (bid >= nrouter) {
        int tt = bid - nrouter;        // [0, 2*4096)
        const float* s = W1; __bf16* d = W1t;
        if (tt >= 4096) { s = W2; d = W2t; tt -= 4096; }
        int e = tt >> 9, rem = tt & 511;
        int kt_i = rem >> 6, nt_i = rem & 63;   // 8 ktiles x 64 ntiles
        transpose_tile_k128(s + ((size_t)e << 22), d + ((size_t)e << 22),
                            D_MODEL, D_FF, kt_i * 128, nt_i * 64, tid, buf);
        return;
    }

    int n = bid;
    const float* xr = x + (size_t)n * D_MODEL;
    int d0 = tid * 4;
    float4 xv = *reinterpret_cast<const float4*>(xr + d0);

    union { __bf16 h[4]; ushort4 u; } pk;
    pk.h[0] = (__bf16)xv.x; pk.h[1] = (__bf16)xv.y;
    pk.h[2] = (__bf16)xv.z; pk.h[3] = (__bf16)xv.w;
    *reinterpret_cast<ushort4*>(Xb + (size_t)n * D_MODEL + d0) = pk.u;

    float part[NE];
#pragma unroll
    for (int e = 0; e < NE; ++e) part[e] = 0.f;
    float xs[4] = {xv.x, xv.y, xv.z, xv.w};
#pragma unroll
    for (int j = 0; j < 4; ++j) {
        const float4* wr = reinterpret_cast<const float4*>(Wg + (size_t)(d0 + j) * NE);
        float4 w0 = wr[0], w1 = wr[1];
        part[0] += xs[j] * w0.x; part[1] += xs[j] * w0.y;
        part[2] += xs[j] * w0.z; part[3] += xs[j] * w0.w;
        part[4] += xs[j] * w1.x; part[5] += xs[j] * w1.y;
        part[6] += xs[j] * w1.z; part[7] += xs[j] * w1.w;
    }
#pragma unroll
    for (int off = 32; off > 0; off >>= 1) {
#pragma unroll
        for (int e = 0; e < NE; ++e) part[e] += __shfl_down(part[e], off);
    }
    float* sred = &buf[0][0];
    float* slog = &buf[1][0];
    int wave = tid >> 6, lane = tid & 63;
    if (lane == 0) {
#pragma unroll
        for (int e = 0; e < NE; ++e) sred[wave * NE + e] = part[e];
    }
    __syncthreads();
    if (tid < NE)
        slog[tid] = bg[tid] + sred[tid] + sred[NE + tid] + sred[2 * NE + tid] + sred[3 * NE + tid];
    __syncthreads();
    if (tid == 0) {
        float m0 = -1e30f, m1 = -1e30f; int i0 = 0, i1 = 0;
        for (int e = 0; e < NE; ++e) {
            float l = slog[e];
            if (l > m0)      { m1 = m0; i1 = i0; m0 = l; i0 = e; }
            else if (l > m1) { m1 = l;  i1 = e; }
        }
        float w1 = expf(m1 - m0);
        float s  = 1.f + w1;
        topidx[n * 2 + 0] = i0; topidx[n * 2 + 1] = i1;
        topw[n * 2 + 0] = 1.f / s; topw[n * 2 + 1] = w1 / s;
    }
}

// ---------------- build per-expert padded row lists (align 256) + pairRow ----------------
__global__ __launch_bounds__(256) void build_lists_kernel(
    const int* __restrict__ topidx, const float* __restrict__ topw,
    int* __restrict__ pairTok, float* __restrict__ pairW,
    int* __restrict__ rbe, int* __restrict__ pairRow,
    int npairs, int maxrows, int maxblk)
{
    __shared__ int cnt[NE], cur[NE], pof[NE];
    int tid = threadIdx.x;
    if (tid < NE) { cnt[tid] = 0; cur[tid] = 0; }
    for (int i = tid; i < maxrows; i += 256) pairTok[i] = -1;
    for (int i = tid; i < maxblk; i += 256) rbe[i] = -1;
    __syncthreads();
    for (int p = tid; p < npairs; p += 256) atomicAdd(&cnt[topidx[p]], 1);
    __syncthreads();
    if (tid == 0) {
        int off = 0;
        for (int e = 0; e < NE; ++e) { pof[e] = off; off += (cnt[e] + MT - 1) & ~(MT - 1); }
        for (int e = 0; e < NE; ++e) {
            int nb = (cnt[e] + MT - 1) / MT;
            for (int j = 0; j < nb; ++j) rbe[pof[e] / MT + j] = e;
        }
    }
    __syncthreads();
    for (int p = tid; p < npairs; p += 256) {
        int e = topidx[p];
        int pos = atomicAdd(&cur[e], 1);
        int r = pof[e] + pos;
        pairTok[r]  = p >> 1;
        pairW[r]    = topw[p];
        pairRow[p]  = r;
    }
}

// ---- GEMM1 (R13 body) + tail W3-transpose jobs overlapped under this dispatch ----
// Active blocks: full 256x128 dual-B gemm, then reuse smem as f32 scratch for
// their share of W3 tiles. Inactive (e<0) blocks do their tiles immediately.
// gemm2 (sole W3t consumer) launches after gemm1 -> all tiles complete.
// R8 lesson: acc=128 regs, no min-waves launch_bounds.
__global__ __launch_bounds__(512) void gemm1_mfma(
    const __bf16* __restrict__ Xb, const __bf16* __restrict__ W1t,
    const __bf16* __restrict__ W2t, const float* __restrict__ b1,
    const float* __restrict__ b2, const int* __restrict__ pairTok,
    const int* __restrict__ rbe, const __bf16* __restrict__ zpg,
    __bf16* __restrict__ hidden,
    const float* __restrict__ W3, __bf16* __restrict__ W3t, int maxblk)
{
    __shared__ __bf16 smem[2][32768];
    int wgid = xcd_swizzle(blockIdx.x, gridDim.x);
    int b = wgid % maxblk;
    int e = rbe[b];
    int fblk = (wgid / maxblk) * 128;
    int tid = threadIdx.x, w = tid >> 6, l = tid & 63;

    if (e >= 0) {
        int srcslot = (l & 7) ^ (l >> 3);   // LDS[row][s] = src[row][s ^ (row&7)]
        int r0 = b * MT;

        const __bf16* aptr[4];
#pragma unroll
        for (int j = 0; j < 4; ++j) {
            int row = w * 32 + j * 8 + (l >> 3);
            int tok = pairTok[r0 + row];
            aptr[j] = (tok >= 0 ? Xb + (size_t)tok * D_MODEL : zpg) + srcslot * 8;
        }
        const __bf16* b1base = W1t + ((size_t)e << 22)
            + (size_t)(fblk + w * 16 + (l >> 3)) * D_MODEL + srcslot * 8;
        const __bf16* b2base = W2t + ((size_t)e << 22)
            + (size_t)(fblk + w * 16 + (l >> 3)) * D_MODEL + srcslot * 8;

        int wm = (w >> 1) * 64, wf = (w & 1) * 64;
        int lm = l & 15;

        f32x4 c1[4][4], c2[4][4];
#pragma unroll
        for (int mi = 0; mi < 4; ++mi)
#pragma unroll
            for (int fj = 0; fj < 4; ++fj) {
                c1[mi][fj] = (f32x4){0.f, 0.f, 0.f, 0.f};
                c2[mi][fj] = (f32x4){0.f, 0.f, 0.f, 0.f};
            }

        auto stage = [&](int buf, int k0) {
            __bf16* base = &smem[buf][0];
#pragma unroll
            for (int j = 0; j < 4; ++j)
                async16(aptr[j] + k0, base + w * 2048 + j * 512);
            async16(b1base + k0,               base + 16384 + w * 1024);
            async16(b1base + 8 * D_MODEL + k0, base + 16384 + w * 1024 + 512);
            async16(b2base + k0,               base + 24576 + w * 1024);
            async16(b2base + 8 * D_MODEL + k0, base + 24576 + w * 1024 + 512);
        };

        stage(0, 0);
        __syncthreads();
        const int NT = D_MODEL / 64;   // 16
        for (int t = 0; t < NT; ++t) {
            int cur = t & 1;
            if (t + 1 < NT) stage(cur ^ 1, (t + 1) * 64);
            const __bf16* sb = &smem[cur][0];
#pragma unroll
            for (int ks = 0; ks < 2; ++ks) {
                int sl = (((ks * 4 + (l >> 4)) ^ (l & 7)) << 3);   // read XOR = row&7
                bf16x8 a[4];
#pragma unroll
                for (int mi = 0; mi < 4; ++mi)
                    a[mi] = *reinterpret_cast<const bf16x8*>(sb + (wm + mi * 16 + lm) * 64 + sl);
#pragma unroll
                for (int fj = 0; fj < 4; ++fj) {
                    int frow = wf + fj * 16 + lm;
                    bf16x8 bv1 = *reinterpret_cast<const bf16x8*>(sb + 16384 + frow * 64 + sl);
                    bf16x8 bv2 = *reinterpret_cast<const bf16x8*>(sb + 24576 + frow * 64 + sl);
#pragma unroll
                    for (int mi = 0; mi < 4; ++mi) {
                        c1[mi][fj] = __builtin_amdgcn_mfma_f32_16x16x32_bf16(a[mi], bv1, c1[mi][fj], 0, 0, 0);
                        c2[mi][fj] = __builtin_amdgcn_mfma_f32_16x16x32_bf16(a[mi], bv2, c2[mi][fj], 0, 0, 0);
                    }
                }
            }
            __syncthreads();
        }

#pragma unroll
        for (int fj = 0; fj < 4; ++fj) {
            int f = fblk + wf + fj * 16 + lm;
            float b1v = b1[e * D_FF + f];
            float b2v = b2[e * D_FF + f];
#pragma unroll
            for (int mi = 0; mi < 4; ++mi)
#pragma unroll
                for (int r = 0; r < 4; ++r) {
                    int m = wm + mi * 16 + (l >> 4) * 4 + r;
                    float h1 = c1[mi][fj][r] + b1v;
                    float h2 = c2[mi][fj][r] + b2v;
                    float g = 0.5f * h1 * (1.f + erff(h1 * 0.70710678118654752f));
                    hidden[(size_t)(r0 + m) * D_FF + f] = (__bf16)(g * h2);
                }
        }
        __syncthreads();   // smem reuse below
    }

    // ---- W3 transpose tail: tiles {wgid + k*nwg} (bijective coverage) ----
    // Two 256-thread subgroups, each its own 33.3KB f32 buffer in smem.
    {
        int nwg = gridDim.x;
        float* smf = reinterpret_cast<float*>(&smem[0][0]);
        int sub = tid >> 8;
        float (*tb)[65] = reinterpret_cast<float (*)[65]>(smf + sub * 8520);
        int stid = tid & 255;
        for (int t0 = wgid; t0 < NW3T; t0 += 2 * nwg) {
            int t1 = t0 + nwg;
            if (t1 >= NW3T) t1 = t0;      // duplicate work: identical bytes, race-benign
            int tt = sub ? t1 : t0;
            int te = tt >> 9, rem = tt & 511;
            int kt_i = rem >> 4, nt_i = rem & 15;   // 32 ktiles x 16 ntiles
            transpose_tile_k128(W3 + ((size_t)te << 22), W3t + ((size_t)te << 22),
                                D_FF, D_MODEL, kt_i * 128, nt_i * 64, stid, tb);
            __syncthreads();
        }
    }
}

// ---------------- GEMM2: 128x128, BK=64, K=4096, po-store + XCD swizzle ----------------
__global__ __launch_bounds__(512, 4) void gemm2_mfma(
    const __bf16* __restrict__ hidden, const __bf16* __restrict__ W3t,
    const float* __restrict__ b3, const int* __restrict__ rbe,
    float* __restrict__ po, int nrb)
{
    int wgid = xcd_swizzle(blockIdx.x, gridDim.x);
    int rb = wgid % nrb;           // 128-row block
    int e = rbe[rb >> 1];
    if (e < 0) return;
    int dblk = (wgid / nrb) * 128;

    __shared__ __bf16 smem[2][16384];

    int tid = threadIdx.x, w = tid >> 6, l = tid & 63;
    int ss8 = (l & 7) ^ (l >> 3);
    int r0m = rb * 128;

    const __bf16* abase = hidden + (size_t)(r0m + w * 16 + (l >> 3)) * D_FF + ss8 * 8;
    const __bf16* bbase = W3t + ((size_t)e << 22)
        + (size_t)(dblk + w * 16 + (l >> 3)) * D_FF + ss8 * 8;

    int wm = (w >> 1) * 32, wn = (w & 1) * 64;
    int lm = l & 15;

    f32x4 c[2][4];
#pragma unroll
    for (int mi = 0; mi < 2; ++mi)
#pragma unroll
        for (int nj = 0; nj < 4; ++nj) c[mi][nj] = (f32x4){0.f, 0.f, 0.f, 0.f};

    auto stage = [&](int buf, int k0) {
        __bf16* base = &smem[buf][0];
        async16(abase + k0,              base + w * 1024 + l * 8);
        async16(abase + 8 * D_FF + k0,   base + w * 1024 + 512 + l * 8);
        async16(bbase + k0,              base + 8192 + w * 1024 + l * 8);
        async16(bbase + 8 * D_FF + k0,   base + 8192 + w * 1024 + 512 + l * 8);
    };

    stage(0, 0);
    __syncthreads();
    const int NT = D_FF / 64;   // 64
    for (int t = 0; t < NT; ++t) {
        int cur = t & 1;
        if (t + 1 < NT) stage(cur ^ 1, (t + 1) * 64);
        const __bf16* sb = &smem[cur][0];
#pragma unroll
        for (int ks = 0; ks < 2; ++ks) {
            int sl = (((ks * 4 + (l >> 4)) ^ (l & 7)) << 3);
            bf16x8 a[2];
#pragma unroll
            for (int mi = 0; mi < 2; ++mi)
                a[mi] = *reinterpret_cast<const bf16x8*>(sb + (wm + mi * 16 + lm) * 64 + sl);
#pragma unroll
            for (int nj = 0; nj < 4; ++nj) {
                bf16x8 bv = *reinterpret_cast<const bf16x8*>(sb + 8192 + (wn + nj * 16 + lm) * 64 + sl);
#pragma unroll
                for (int mi = 0; mi < 2; ++mi)
                    c[mi][nj] = __builtin_amdgcn_mfma_f32_16x16x32_bf16(a[mi], bv, c[mi][nj], 0, 0, 0);
            }
        }
        __syncthreads();
    }

#pragma unroll
    for (int nj = 0; nj < 4; ++nj) {
        int d = dblk + wn + nj * 16 + lm;
        float b3v = b3[e * D_MODEL + d];
#pragma unroll
        for (int mi = 0; mi < 2; ++mi)
#pragma unroll
            for (int r = 0; r < 4; ++r) {
                int m = wm + mi * 16 + (l >> 4) * 4 + r;
                po[(size_t)(r0m + m) * D_MODEL + d] = c[mi][nj][r] + b3v;
            }
    }
}

// ---------------- combine: out[t] = w0*po[r0] + w1*po[r1] ----------------
__global__ __launch_bounds__(256) void combine_kernel(
    const float* __restrict__ po, const float* __restrict__ topw,
    const int* __restrict__ pairRow, float* __restrict__ out)
{
    int t = blockIdx.x, tid = threadIdx.x;
    int d = tid * 4;
    float w0 = topw[t * 2], w1 = topw[t * 2 + 1];
    int r0 = pairRow[t * 2], r1 = pairRow[t * 2 + 1];
    float4 v0 = *reinterpret_cast<const float4*>(po + (size_t)r0 * D_MODEL + d);
    float4 v1 = *reinterpret_cast<const float4*>(po + (size_t)r1 * D_MODEL + d);
    float4 o;
    o.x = w0 * v0.x + w1 * v1.x;
    o.y = w0 * v0.y + w1 * v1.y;
    o.z = w0 * v0.z + w1 * v1.z;
    o.w = w0 * v0.w + w1 * v1.w;
    *reinterpret_cast<float4*>(out + (size_t)t * D_MODEL + d) = o;
}

extern "C" void kernel_launch(void* const* d_in, const int* in_sizes, int n_in,
                              void* d_out, int out_size, void* d_ws, size_t ws_size,
                              hipStream_t stream)
{
    const float* x  = (const float*)d_in[0];
    const float* Wg = (const float*)d_in[1];
    const float* bg = (const float*)d_in[2];
    const float* W1 = (const float*)d_in[3];
    const float* b1 = (const float*)d_in[4];
    const float* W2 = (const float*)d_in[5];
    const float* b2 = (const float*)d_in[6];
    const float* W3 = (const float*)d_in[7];
    const float* b3 = (const float*)d_in[8];
    float* out = (float*)d_out;

    int N = in_sizes[0] / D_MODEL;     // 2048
    int npairs = N * 2;
    int maxblk = npairs / MT + NE;     // 24
    int maxrows = maxblk * MT;         // 6144

    char* ws = (char*)d_ws;
    size_t off = 0;
    auto alloc = [&](size_t bytes) -> void* {
        void* p = ws + off;
        off = (off + bytes + 255) & ~(size_t)255;
        return p;
    };
    int*    topidx  = (int*)   alloc((size_t)npairs * 4);
    float*  topw    = (float*) alloc((size_t)npairs * 4);
    int*    pairTok = (int*)   alloc((size_t)maxrows * 4);
    float*  pairW   = (float*) alloc((size_t)maxrows * 4);
    int*    rbe     = (int*)   alloc((size_t)maxblk * 4);
    int*    pairRow = (int*)   alloc((size_t)npairs * 4);
    __bf16* Xb      = (__bf16*)alloc((size_t)N * D_MODEL * 2);
    __bf16* hidden  = (__bf16*)alloc((size_t)maxrows * D_FF * 2);
    __bf16* zpg     = (__bf16*)alloc(4096);
    const size_t WSZ = (size_t)NE * D_MODEL * D_FF * 2;   // 64 MB per matrix
    __bf16* W1t = (__bf16*)alloc(WSZ);
    __bf16* W2t = (__bf16*)alloc(WSZ);
    __bf16* W3t = (__bf16*)alloc(WSZ);
    float*  po  = (float*)W1t;   // overlay: W1t dead after gemm1 (25MB < 64MB)
    (void)ws_size; (void)n_in; (void)pairW;

    hipMemsetAsync(zpg, 0, 4096, stream);

    // router + T(W1) + T(W2) only — T(W3) rides under gemm1
    fused_pre<<<N + 2 * 4096, 256, 0, stream>>>(
        x, Wg, bg, topidx, topw, Xb, W1, W2, W1t, W2t, N);
    build_lists_kernel<<<1, 256, 0, stream>>>(topidx, topw, pairTok, pairW, rbe,
                                              pairRow, npairs, maxrows, maxblk);
    gemm1_mfma<<<maxblk * (D_FF / 128), 512, 0, stream>>>(
        Xb, W1t, W2t, b1, b2, pairTok, rbe, zpg, hidden, W3, W3t, maxblk);
    gemm2_mfma<<<(maxblk * 2) * (D_MODEL / 128), 512, 0, stream>>>(
        hidden, W3t, b3, rbe, po, maxblk * 2);
    combine_kernel<<<N, 256, 0, stream>>>(po, topw, pairRow, out);
}

// Round 16
// 321.228 us; speedup vs baseline: 1.4917x; 1.0226x over previous
//
#include <hip/hip_runtime.h>
#include <hip/hip_bf16.h>
#include <math.h>

#define D_MODEL 1024
#define D_FF    4096
#define NE      8
#define MT      256   // list alignment / gemm1 M tile
#define NW3T    4096  // W3 transpose tiles: 8e x 32kt x 16nt (128k x 64f)

typedef __bf16 bf16x8 __attribute__((ext_vector_type(8)));
typedef float  f32x4  __attribute__((ext_vector_type(4)));
typedef short  s16x8  __attribute__((ext_vector_type(8)));

__device__ __forceinline__ void async16(const void* g, void* l) {
    __builtin_amdgcn_global_load_lds(
        (__attribute__((address_space(1))) uint32_t*)g,
        (__attribute__((address_space(3))) uint32_t*)l, 16, 0, 0);
}

// bijective XCD chunking (m204): contiguous runs of nwg/8 blocks per XCD
__device__ __forceinline__ int xcd_swizzle(int lin, int nwg) {
    if ((nwg & 7) != 0) return lin;
    int q = nwg >> 3;
    return (lin & 7) * q + (lin >> 3);
}

// 128k x 64f transpose+cvt tile: src[K][N] f32 -> dst[N][K] bf16. (R9-verified)
// nt-hinted via ext-vector types (nontemporal builtins reject HIP_vector_type):
// src read-once, dst consumed by a LATER kernel -> skip L2 retention so the
// resident GEMM weight strips stay hot.
__device__ __forceinline__ void transpose_tile_k128(
    const float* __restrict__ s, __bf16* __restrict__ d,
    int K, int N, int kt, int nt, int tid, float (*tile)[65])
{
    int tr = tid >> 4, tc = (tid & 15) * 4;
#pragma unroll
    for (int p = 0; p < 8; ++p) {
        f32x4 v = __builtin_nontemporal_load(reinterpret_cast<const f32x4*>(
            s + (size_t)(kt + tr + p * 16) * N + nt + tc));
        tile[tr + p * 16][tc + 0] = v.x;
        tile[tr + p * 16][tc + 1] = v.y;
        tile[tr + p * 16][tc + 2] = v.z;
        tile[tr + p * 16][tc + 3] = v.w;
    }
    __syncthreads();
    int kq = (tid & 15) * 8;
#pragma unroll
    for (int p = 0; p < 4; ++p) {
        int rr = (tid >> 4) + p * 16;   // f within tile
        union { bf16x8 h; s16x8 i; } pk;
#pragma unroll
        for (int i = 0; i < 8; ++i) pk.h[i] = (__bf16)tile[kq + i][rr];
        __builtin_nontemporal_store(pk.i, reinterpret_cast<s16x8*>(
            d + (size_t)(nt + rr) * K + kt + kq));
    }
}

// -------- fused: router (bid<nrouter) | T(W1) | T(W2)  (W3 rides under gemm1) --------
__global__ __launch_bounds__(256) void fused_pre(
    const float* __restrict__ x, const float* __restrict__ Wg,
    const float* __restrict__ bg, int* __restrict__ topidx,
    float* __restrict__ topw, __bf16* __restrict__ Xb,
    const float* __restrict__ W1, const float* __restrict__ W2,
    __bf16* __restrict__ W1t, __bf16* __restrict__ W2t, int nrouter)
{
    __shared__ float buf[128][65];
    int bid = blockIdx.x, tid = threadIdx.x;

    if (bid >= nrouter) {
        int tt = bid - nrouter;        // [0, 2*4096)
        const float* s = W1; __bf16* d = W1t;
        if (tt >= 4096) { s = W2; d = W2t; tt -= 4096; }
        int e = tt >> 9, rem = tt & 511;
        int kt_i = rem >> 6, nt_i = rem & 63;   // 8 ktiles x 64 ntiles
        transpose_tile_k128(s + ((size_t)e << 22), d + ((size_t)e << 22),
                            D_MODEL, D_FF, kt_i * 128, nt_i * 64, tid, buf);
        return;
    }

    int n = bid;
    const float* xr = x + (size_t)n * D_MODEL;
    int d0 = tid * 4;
    float4 xv = *reinterpret_cast<const float4*>(xr + d0);

    union { __bf16 h[4]; ushort4 u; } pk;
    pk.h[0] = (__bf16)xv.x; pk.h[1] = (__bf16)xv.y;
    pk.h[2] = (__bf16)xv.z; pk.h[3] = (__bf16)xv.w;
    *reinterpret_cast<ushort4*>(Xb + (size_t)n * D_MODEL + d0) = pk.u;

    float part[NE];
#pragma unroll
    for (int e = 0; e < NE; ++e) part[e] = 0.f;
    float xs[4] = {xv.x, xv.y, xv.z, xv.w};
#pragma unroll
    for (int j = 0; j < 4; ++j) {
        const float4* wr = reinterpret_cast<const float4*>(Wg + (size_t)(d0 + j) * NE);
        float4 w0 = wr[0], w1 = wr[1];
        part[0] += xs[j] * w0.x; part[1] += xs[j] * w0.y;
        part[2] += xs[j] * w0.z; part[3] += xs[j] * w0.w;
        part[4] += xs[j] * w1.x; part[5] += xs[j] * w1.y;
        part[6] += xs[j] * w1.z; part[7] += xs[j] * w1.w;
    }
#pragma unroll
    for (int off = 32; off > 0; off >>= 1) {
#pragma unroll
        for (int e = 0; e < NE; ++e) part[e] += __shfl_down(part[e], off);
    }
    float* sred = &buf[0][0];
    float* slog = &buf[1][0];
    int wave = tid >> 6, lane = tid & 63;
    if (lane == 0) {
#pragma unroll
        for (int e = 0; e < NE; ++e) sred[wave * NE + e] = part[e];
    }
    __syncthreads();
    if (tid < NE)
        slog[tid] = bg[tid] + sred[tid] + sred[NE + tid] + sred[2 * NE + tid] + sred[3 * NE + tid];
    __syncthreads();
    if (tid == 0) {
        float m0 = -1e30f, m1 = -1e30f; int i0 = 0, i1 = 0;
        for (int e = 0; e < NE; ++e) {
            float l = slog[e];
            if (l > m0)      { m1 = m0; i1 = i0; m0 = l; i0 = e; }
            else if (l > m1) { m1 = l;  i1 = e; }
        }
        float w1 = expf(m1 - m0);
        float s  = 1.f + w1;
        topidx[n * 2 + 0] = i0; topidx[n * 2 + 1] = i1;
        topw[n * 2 + 0] = 1.f / s; topw[n * 2 + 1] = w1 / s;
    }
}

// ---------------- build per-expert padded row lists (align 256) + pairRow ----------------
__global__ __launch_bounds__(256) void build_lists_kernel(
    const int* __restrict__ topidx, const float* __restrict__ topw,
    int* __restrict__ pairTok, float* __restrict__ pairW,
    int* __restrict__ rbe, int* __restrict__ pairRow,
    int npairs, int maxrows, int maxblk)
{
    __shared__ int cnt[NE], cur[NE], pof[NE];
    int tid = threadIdx.x;
    if (tid < NE) { cnt[tid] = 0; cur[tid] = 0; }
    for (int i = tid; i < maxrows; i += 256) pairTok[i] = -1;
    for (int i = tid; i < maxblk; i += 256) rbe[i] = -1;
    __syncthreads();
    for (int p = tid; p < npairs; p += 256) atomicAdd(&cnt[topidx[p]], 1);
    __syncthreads();
    if (tid == 0) {
        int off = 0;
        for (int e = 0; e < NE; ++e) { pof[e] = off; off += (cnt[e] + MT - 1) & ~(MT - 1); }
        for (int e = 0; e < NE; ++e) {
            int nb = (cnt[e] + MT - 1) / MT;
            for (int j = 0; j < nb; ++j) rbe[pof[e] / MT + j] = e;
        }
    }
    __syncthreads();
    for (int p = tid; p < npairs; p += 256) {
        int e = topidx[p];
        int pos = atomicAdd(&cur[e], 1);
        int r = pof[e] + pos;
        pairTok[r]  = p >> 1;
        pairW[r]    = topw[p];
        pairRow[p]  = r;
    }
}

// ---- GEMM1 (R13 body) + W3-transpose tail overlapped under this dispatch ----
// R8 lesson: acc=128 regs, no min-waves launch_bounds.
__global__ __launch_bounds__(512) void gemm1_mfma(
    const __bf16* __restrict__ Xb, const __bf16* __restrict__ W1t,
    const __bf16* __restrict__ W2t, const float* __restrict__ b1,
    const float* __restrict__ b2, const int* __restrict__ pairTok,
    const int* __restrict__ rbe, const __bf16* __restrict__ zpg,
    __bf16* __restrict__ hidden,
    const float* __restrict__ W3, __bf16* __restrict__ W3t, int maxblk)
{
    __shared__ __bf16 smem[2][32768];
    int wgid = xcd_swizzle(blockIdx.x, gridDim.x);
    int b = wgid % maxblk;
    int e = rbe[b];
    int fblk = (wgid / maxblk) * 128;
    int tid = threadIdx.x, w = tid >> 6, l = tid & 63;

    if (e >= 0) {
        int srcslot = (l & 7) ^ (l >> 3);   // LDS[row][s] = src[row][s ^ (row&7)]
        int r0 = b * MT;

        const __bf16* aptr[4];
#pragma unroll
        for (int j = 0; j < 4; ++j) {
            int row = w * 32 + j * 8 + (l >> 3);
            int tok = pairTok[r0 + row];
            aptr[j] = (tok >= 0 ? Xb + (size_t)tok * D_MODEL : zpg) + srcslot * 8;
        }
        const __bf16* b1base = W1t + ((size_t)e << 22)
            + (size_t)(fblk + w * 16 + (l >> 3)) * D_MODEL + srcslot * 8;
        const __bf16* b2base = W2t + ((size_t)e << 22)
            + (size_t)(fblk + w * 16 + (l >> 3)) * D_MODEL + srcslot * 8;

        int wm = (w >> 1) * 64, wf = (w & 1) * 64;
        int lm = l & 15;

        f32x4 c1[4][4], c2[4][4];
#pragma unroll
        for (int mi = 0; mi < 4; ++mi)
#pragma unroll
            for (int fj = 0; fj < 4; ++fj) {
                c1[mi][fj] = (f32x4){0.f, 0.f, 0.f, 0.f};
                c2[mi][fj] = (f32x4){0.f, 0.f, 0.f, 0.f};
            }

        auto stage = [&](int buf, int k0) {
            __bf16* base = &smem[buf][0];
#pragma unroll
            for (int j = 0; j < 4; ++j)
                async16(aptr[j] + k0, base + w * 2048 + j * 512);
            async16(b1base + k0,               base + 16384 + w * 1024);
            async16(b1base + 8 * D_MODEL + k0, base + 16384 + w * 1024 + 512);
            async16(b2base + k0,               base + 24576 + w * 1024);
            async16(b2base + 8 * D_MODEL + k0, base + 24576 + w * 1024 + 512);
        };

        stage(0, 0);
        __syncthreads();
        const int NT = D_MODEL / 64;   // 16
        for (int t = 0; t < NT; ++t) {
            int cur = t & 1;
            if (t + 1 < NT) stage(cur ^ 1, (t + 1) * 64);
            const __bf16* sb = &smem[cur][0];
#pragma unroll
            for (int ks = 0; ks < 2; ++ks) {
                int sl = (((ks * 4 + (l >> 4)) ^ (l & 7)) << 3);   // read XOR = row&7
                bf16x8 a[4];
#pragma unroll
                for (int mi = 0; mi < 4; ++mi)
                    a[mi] = *reinterpret_cast<const bf16x8*>(sb + (wm + mi * 16 + lm) * 64 + sl);
#pragma unroll
                for (int fj = 0; fj < 4; ++fj) {
                    int frow = wf + fj * 16 + lm;
                    bf16x8 bv1 = *reinterpret_cast<const bf16x8*>(sb + 16384 + frow * 64 + sl);
                    bf16x8 bv2 = *reinterpret_cast<const bf16x8*>(sb + 24576 + frow * 64 + sl);
#pragma unroll
                    for (int mi = 0; mi < 4; ++mi) {
                        c1[mi][fj] = __builtin_amdgcn_mfma_f32_16x16x32_bf16(a[mi], bv1, c1[mi][fj], 0, 0, 0);
                        c2[mi][fj] = __builtin_amdgcn_mfma_f32_16x16x32_bf16(a[mi], bv2, c2[mi][fj], 0, 0, 0);
                    }
                }
            }
            __syncthreads();
        }

#pragma unroll
        for (int fj = 0; fj < 4; ++fj) {
            int f = fblk + wf + fj * 16 + lm;
            float b1v = b1[e * D_FF + f];
            float b2v = b2[e * D_FF + f];
#pragma unroll
            for (int mi = 0; mi < 4; ++mi)
#pragma unroll
                for (int r = 0; r < 4; ++r) {
                    int m = wm + mi * 16 + (l >> 4) * 4 + r;
                    float h1 = c1[mi][fj][r] + b1v;
                    float h2 = c2[mi][fj][r] + b2v;
                    float g = 0.5f * h1 * (1.f + erff(h1 * 0.70710678118654752f));
                    hidden[(size_t)(r0 + m) * D_FF + f] = (__bf16)(g * h2);
                }
        }
        __syncthreads();   // smem reuse below
    }

    // ---- W3 transpose tail: tiles {wgid + k*nwg} (bijective coverage) ----
    {
        int nwg = gridDim.x;
        float* smf = reinterpret_cast<float*>(&smem[0][0]);
        int sub = tid >> 8;
        float (*tb)[65] = reinterpret_cast<float (*)[65]>(smf + sub * 8520);
        int stid = tid & 255;
        for (int t0 = wgid; t0 < NW3T; t0 += 2 * nwg) {
            int t1 = t0 + nwg;
            if (t1 >= NW3T) t1 = t0;      // duplicate work: identical bytes, race-benign
            int tt = sub ? t1 : t0;
            int te = tt >> 9, rem = tt & 511;
            int kt_i = rem >> 4, nt_i = rem & 15;   // 32 ktiles x 16 ntiles
            transpose_tile_k128(W3 + ((size_t)te << 22), W3t + ((size_t)te << 22),
                                D_FF, D_MODEL, kt_i * 128, nt_i * 64, stid, tb);
            __syncthreads();
        }
    }
}

// ---------------- GEMM2: 128x128, BK=64, K=4096, po-store + XCD swizzle ----------------
__global__ __launch_bounds__(512, 4) void gemm2_mfma(
    const __bf16* __restrict__ hidden, const __bf16* __restrict__ W3t,
    const float* __restrict__ b3, const int* __restrict__ rbe,
    float* __restrict__ po, int nrb)
{
    int wgid = xcd_swizzle(blockIdx.x, gridDim.x);
    int rb = wgid % nrb;           // 128-row block
    int e = rbe[rb >> 1];
    if (e < 0) return;
    int dblk = (wgid / nrb) * 128;

    __shared__ __bf16 smem[2][16384];

    int tid = threadIdx.x, w = tid >> 6, l = tid & 63;
    int ss8 = (l & 7) ^ (l >> 3);
    int r0m = rb * 128;

    const __bf16* abase = hidden + (size_t)(r0m + w * 16 + (l >> 3)) * D_FF + ss8 * 8;
    const __bf16* bbase = W3t + ((size_t)e << 22)
        + (size_t)(dblk + w * 16 + (l >> 3)) * D_FF + ss8 * 8;

    int wm = (w >> 1) * 32, wn = (w & 1) * 64;
    int lm = l & 15;

    f32x4 c[2][4];
#pragma unroll
    for (int mi = 0; mi < 2; ++mi)
#pragma unroll
        for (int nj = 0; nj < 4; ++nj) c[mi][nj] = (f32x4){0.f, 0.f, 0.f, 0.f};

    auto stage = [&](int buf, int k0) {
        __bf16* base = &smem[buf][0];
        async16(abase + k0,              base + w * 1024 + l * 8);
        async16(abase + 8 * D_FF + k0,   base + w * 1024 + 512 + l * 8);
        async16(bbase + k0,              base + 8192 + w * 1024 + l * 8);
        async16(bbase + 8 * D_FF + k0,   base + 8192 + w * 1024 + 512 + l * 8);
    };

    stage(0, 0);
    __syncthreads();
    const int NT = D_FF / 64;   // 64
    for (int t = 0; t < NT; ++t) {
        int cur = t & 1;
        if (t + 1 < NT) stage(cur ^ 1, (t + 1) * 64);
        const __bf16* sb = &smem[cur][0];
#pragma unroll
        for (int ks = 0; ks < 2; ++ks) {
            int sl = (((ks * 4 + (l >> 4)) ^ (l & 7)) << 3);
            bf16x8 a[2];
#pragma unroll
            for (int mi = 0; mi < 2; ++mi)
                a[mi] = *reinterpret_cast<const bf16x8*>(sb + (wm + mi * 16 + lm) * 64 + sl);
#pragma unroll
            for (int nj = 0; nj < 4; ++nj) {
                bf16x8 bv = *reinterpret_cast<const bf16x8*>(sb + 8192 + (wn + nj * 16 + lm) * 64 + sl);
#pragma unroll
                for (int mi = 0; mi < 2; ++mi)
                    c[mi][nj] = __builtin_amdgcn_mfma_f32_16x16x32_bf16(a[mi], bv, c[mi][nj], 0, 0, 0);
            }
        }
        __syncthreads();
    }

#pragma unroll
    for (int nj = 0; nj < 4; ++nj) {
        int d = dblk + wn + nj * 16 + lm;
        float b3v = b3[e * D_MODEL + d];
#pragma unroll
        for (int mi = 0; mi < 2; ++mi)
#pragma unroll
            for (int r = 0; r < 4; ++r) {
                int m = wm + mi * 16 + (l >> 4) * 4 + r;
                po[(size_t)(r0m + m) * D_MODEL + d] = c[mi][nj][r] + b3v;
            }
    }
}

// ---------------- combine: out[t] = w0*po[r0] + w1*po[r1] ----------------
__global__ __launch_bounds__(256) void combine_kernel(
    const float* __restrict__ po, const float* __restrict__ topw,
    const int* __restrict__ pairRow, float* __restrict__ out)
{
    int t = blockIdx.x, tid = threadIdx.x;
    int d = tid * 4;
    float w0 = topw[t * 2], w1 = topw[t * 2 + 1];
    int r0 = pairRow[t * 2], r1 = pairRow[t * 2 + 1];
    float4 v0 = *reinterpret_cast<const float4*>(po + (size_t)r0 * D_MODEL + d);
    float4 v1 = *reinterpret_cast<const float4*>(po + (size_t)r1 * D_MODEL + d);
    float4 o;
    o.x = w0 * v0.x + w1 * v1.x;
    o.y = w0 * v0.y + w1 * v1.y;
    o.z = w0 * v0.z + w1 * v1.z;
    o.w = w0 * v0.w + w1 * v1.w;
    *reinterpret_cast<float4*>(out + (size_t)t * D_MODEL + d) = o;
}

extern "C" void kernel_launch(void* const* d_in, const int* in_sizes, int n_in,
                              void* d_out, int out_size, void* d_ws, size_t ws_size,
                              hipStream_t stream)
{
    const float* x  = (const float*)d_in[0];
    const float* Wg = (const float*)d_in[1];
    const float* bg = (const float*)d_in[2];
    const float* W1 = (const float*)d_in[3];
    const float* b1 = (const float*)d_in[4];
    const float* W2 = (const float*)d_in[5];
    const float* b2 = (const float*)d_in[6];
    const float* W3 = (const float*)d_in[7];
    const float* b3 = (const float*)d_in[8];
    float* out = (float*)d_out;

    int N = in_sizes[0] / D_MODEL;     // 2048
    int npairs = N * 2;
    int maxblk = npairs / MT + NE;     // 24
    int maxrows = maxblk * MT;         // 6144

    char* ws = (char*)d_ws;
    size_t off = 0;
    auto alloc = [&](size_t bytes) -> void* {
        void* p = ws + off;
        off = (off + bytes + 255) & ~(size_t)255;
        return p;
    };
    int*    topidx  = (int*)   alloc((size_t)npairs * 4);
    float*  topw    = (float*) alloc((size_t)npairs * 4);
    int*    pairTok = (int*)   alloc((size_t)maxrows * 4);
    float*  pairW   = (float*) alloc((size_t)maxrows * 4);
    int*    rbe     = (int*)   alloc((size_t)maxblk * 4);
    int*    pairRow = (int*)   alloc((size_t)npairs * 4);
    __bf16* Xb      = (__bf16*)alloc((size_t)N * D_MODEL * 2);
    __bf16* hidden  = (__bf16*)alloc((size_t)maxrows * D_FF * 2);
    __bf16* zpg     = (__bf16*)alloc(4096);
    const size_t WSZ = (size_t)NE * D_MODEL * D_FF * 2;   // 64 MB per matrix
    __bf16* W1t = (__bf16*)alloc(WSZ);
    __bf16* W2t = (__bf16*)alloc(WSZ);
    __bf16* W3t = (__bf16*)alloc(WSZ);
    float*  po  = (float*)W1t;   // overlay: W1t dead after gemm1 (25MB < 64MB)
    (void)ws_size; (void)n_in; (void)pairW;

    hipMemsetAsync(zpg, 0, 4096, stream);

    // router + T(W1) + T(W2) only — T(W3) rides under gemm1
    fused_pre<<<N + 2 * 4096, 256, 0, stream>>>(
        x, Wg, bg, topidx, topw, Xb, W1, W2, W1t, W2t, N);
    build_lists_kernel<<<1, 256, 0, stream>>>(topidx, topw, pairTok, pairW, rbe,
                                              pairRow, npairs, maxrows, maxblk);
    gemm1_mfma<<<maxblk * (D_FF / 128), 512, 0, stream>>>(
        Xb, W1t, W2t, b1, b2, pairTok, rbe, zpg, hidden, W3, W3t, maxblk);
    gemm2_mfma<<<(maxblk * 2) * (D_MODEL / 128), 512, 0, stream>>>(
        hidden, W3t, b3, rbe, po, maxblk * 2);
    combine_kernel<<<N, 256, 0, stream>>>(po, topw, pairRow, out);
}

// Round 17
// 311.549 us; speedup vs baseline: 1.5380x; 1.0311x over previous
//
#include <hip/hip_runtime.h>
#include <hip/hip_bf16.h>
#include <math.h>

#define D_MODEL 1024
#define D_FF    4096
#define NE      8
#define MT      256   // list alignment / gemm1 M tile
#define NW3T    4096  // W3 transpose tiles: 8e x 32kt x 16nt (128k x 64f)

typedef __bf16 bf16x8 __attribute__((ext_vector_type(8)));
typedef float  f32x4  __attribute__((ext_vector_type(4)));
typedef short  s16x8  __attribute__((ext_vector_type(8)));

__device__ __forceinline__ void async16(const void* g, void* l) {
    __builtin_amdgcn_global_load_lds(
        (__attribute__((address_space(1))) uint32_t*)g,
        (__attribute__((address_space(3))) uint32_t*)l, 16, 0, 0);
}

// bijective XCD chunking (m204): contiguous runs of nwg/8 blocks per XCD
__device__ __forceinline__ int xcd_swizzle(int lin, int nwg) {
    if ((nwg & 7) != 0) return lin;
    int q = nwg >> 3;
    return (lin & 7) * q + (lin >> 3);
}

// 128k x 64f transpose+cvt tile: src[K][N] f32 -> dst[N][K] bf16. (R9-verified)
// NT: nontemporal hints — use ONLY in pure-streaming kernels (fused_pre). In
// gemm1's tail they cost +18us (R16 A/B: L2-bypass serializes the tail).
template <bool NT>
__device__ __forceinline__ void transpose_tile_k128(
    const float* __restrict__ s, __bf16* __restrict__ d,
    int K, int N, int kt, int nt, int tid, float (*tile)[65])
{
    int tr = tid >> 4, tc = (tid & 15) * 4;
#pragma unroll
    for (int p = 0; p < 8; ++p) {
        const f32x4* sp = reinterpret_cast<const f32x4*>(
            s + (size_t)(kt + tr + p * 16) * N + nt + tc);
        f32x4 v = NT ? __builtin_nontemporal_load(sp) : *sp;
        tile[tr + p * 16][tc + 0] = v.x;
        tile[tr + p * 16][tc + 1] = v.y;
        tile[tr + p * 16][tc + 2] = v.z;
        tile[tr + p * 16][tc + 3] = v.w;
    }
    __syncthreads();
    int kq = (tid & 15) * 8;
#pragma unroll
    for (int p = 0; p < 4; ++p) {
        int rr = (tid >> 4) + p * 16;   // f within tile
        union { bf16x8 h; s16x8 i; } pk;
#pragma unroll
        for (int i = 0; i < 8; ++i) pk.h[i] = (__bf16)tile[kq + i][rr];
        s16x8* dp = reinterpret_cast<s16x8*>(d + (size_t)(nt + rr) * K + kt + kq);
        if (NT) __builtin_nontemporal_store(pk.i, dp); else *dp = pk.i;
    }
}

// -------- fused: router (bid<nrouter) | T(W1) | T(W2)  (W3 rides under gemm1) --------
__global__ __launch_bounds__(256) void fused_pre(
    const float* __restrict__ x, const float* __restrict__ Wg,
    const float* __restrict__ bg, int* __restrict__ topidx,
    float* __restrict__ topw, __bf16* __restrict__ Xb,
    const float* __restrict__ W1, const float* __restrict__ W2,
    __bf16* __restrict__ W1t, __bf16* __restrict__ W2t, int nrouter)
{
    __shared__ float buf[128][65];
    int bid = blockIdx.x, tid = threadIdx.x;

    if (bid >= nrouter) {
        int tt = bid - nrouter;        // [0, 2*4096)
        const float* s = W1; __bf16* d = W1t;
        if (tt >= 4096) { s = W2; d = W2t; tt -= 4096; }
        int e = tt >> 9, rem = tt & 511;
        int kt_i = rem >> 6, nt_i = rem & 63;   // 8 ktiles x 64 ntiles
        transpose_tile_k128<true>(s + ((size_t)e << 22), d + ((size_t)e << 22),
                                  D_MODEL, D_FF, kt_i * 128, nt_i * 64, tid, buf);
        return;
    }

    int n = bid;
    const float* xr = x + (size_t)n * D_MODEL;
    int d0 = tid * 4;
    float4 xv = *reinterpret_cast<const float4*>(xr + d0);

    union { __bf16 h[4]; ushort4 u; } pk;
    pk.h[0] = (__bf16)xv.x; pk.h[1] = (__bf16)xv.y;
    pk.h[2] = (__bf16)xv.z; pk.h[3] = (__bf16)xv.w;
    *reinterpret_cast<ushort4*>(Xb + (size_t)n * D_MODEL + d0) = pk.u;

    float part[NE];
#pragma unroll
    for (int e = 0; e < NE; ++e) part[e] = 0.f;
    float xs[4] = {xv.x, xv.y, xv.z, xv.w};
#pragma unroll
    for (int j = 0; j < 4; ++j) {
        const float4* wr = reinterpret_cast<const float4*>(Wg + (size_t)(d0 + j) * NE);
        float4 w0 = wr[0], w1 = wr[1];
        part[0] += xs[j] * w0.x; part[1] += xs[j] * w0.y;
        part[2] += xs[j] * w0.z; part[3] += xs[j] * w0.w;
        part[4] += xs[j] * w1.x; part[5] += xs[j] * w1.y;
        part[6] += xs[j] * w1.z; part[7] += xs[j] * w1.w;
    }
#pragma unroll
    for (int off = 32; off > 0; off >>= 1) {
#pragma unroll
        for (int e = 0; e < NE; ++e) part[e] += __shfl_down(part[e], off);
    }
    float* sred = &buf[0][0];
    float* slog = &buf[1][0];
    int wave = tid >> 6, lane = tid & 63;
    if (lane == 0) {
#pragma unroll
        for (int e = 0; e < NE; ++e) sred[wave * NE + e] = part[e];
    }
    __syncthreads();
    if (tid < NE)
        slog[tid] = bg[tid] + sred[tid] + sred[NE + tid] + sred[2 * NE + tid] + sred[3 * NE + tid];
    __syncthreads();
    if (tid == 0) {
        float m0 = -1e30f, m1 = -1e30f; int i0 = 0, i1 = 0;
        for (int e = 0; e < NE; ++e) {
            float l = slog[e];
            if (l > m0)      { m1 = m0; i1 = i0; m0 = l; i0 = e; }
            else if (l > m1) { m1 = l;  i1 = e; }
        }
        float w1 = expf(m1 - m0);
        float s  = 1.f + w1;
        topidx[n * 2 + 0] = i0; topidx[n * 2 + 1] = i1;
        topw[n * 2 + 0] = 1.f / s; topw[n * 2 + 1] = w1 / s;
    }
}

// ---------------- build per-expert padded row lists (align 256) + pairRow ----------------
__global__ __launch_bounds__(256) void build_lists_kernel(
    const int* __restrict__ topidx, const float* __restrict__ topw,
    int* __restrict__ pairTok, float* __restrict__ pairW,
    int* __restrict__ rbe, int* __restrict__ pairRow,
    int npairs, int maxrows, int maxblk)
{
    __shared__ int cnt[NE], cur[NE], pof[NE];
    int tid = threadIdx.x;
    if (tid < NE) { cnt[tid] = 0; cur[tid] = 0; }
    for (int i = tid; i < maxrows; i += 256) pairTok[i] = -1;
    for (int i = tid; i < maxblk; i += 256) rbe[i] = -1;
    __syncthreads();
    for (int p = tid; p < npairs; p += 256) atomicAdd(&cnt[topidx[p]], 1);
    __syncthreads();
    if (tid == 0) {
        int off = 0;
        for (int e = 0; e < NE; ++e) { pof[e] = off; off += (cnt[e] + MT - 1) & ~(MT - 1); }
        for (int e = 0; e < NE; ++e) {
            int nb = (cnt[e] + MT - 1) / MT;
            for (int j = 0; j < nb; ++j) rbe[pof[e] / MT + j] = e;
        }
    }
    __syncthreads();
    for (int p = tid; p < npairs; p += 256) {
        int e = topidx[p];
        int pos = atomicAdd(&cur[e], 1);
        int r = pof[e] + pos;
        pairTok[r]  = p >> 1;
        pairW[r]    = topw[p];
        pairRow[p]  = r;
    }
}

// ---- GEMM1 (R13 body) + W3-transpose tail (plain loads/stores, R14 behavior) ----
// R8 lesson: acc=128 regs, no min-waves launch_bounds.
__global__ __launch_bounds__(512) void gemm1_mfma(
    const __bf16* __restrict__ Xb, const __bf16* __restrict__ W1t,
    const __bf16* __restrict__ W2t, const float* __restrict__ b1,
    const float* __restrict__ b2, const int* __restrict__ pairTok,
    const int* __restrict__ rbe, const __bf16* __restrict__ zpg,
    __bf16* __restrict__ hidden,
    const float* __restrict__ W3, __bf16* __restrict__ W3t, int maxblk)
{
    __shared__ __bf16 smem[2][32768];
    int wgid = xcd_swizzle(blockIdx.x, gridDim.x);
    int b = wgid % maxblk;
    int e = rbe[b];
    int fblk = (wgid / maxblk) * 128;
    int tid = threadIdx.x, w = tid >> 6, l = tid & 63;

    if (e >= 0) {
        int srcslot = (l & 7) ^ (l >> 3);   // LDS[row][s] = src[row][s ^ (row&7)]
        int r0 = b * MT;

        const __bf16* aptr[4];
#pragma unroll
        for (int j = 0; j < 4; ++j) {
            int row = w * 32 + j * 8 + (l >> 3);
            int tok = pairTok[r0 + row];
            aptr[j] = (tok >= 0 ? Xb + (size_t)tok * D_MODEL : zpg) + srcslot * 8;
        }
        const __bf16* b1base = W1t + ((size_t)e << 22)
            + (size_t)(fblk + w * 16 + (l >> 3)) * D_MODEL + srcslot * 8;
        const __bf16* b2base = W2t + ((size_t)e << 22)
            + (size_t)(fblk + w * 16 + (l >> 3)) * D_MODEL + srcslot * 8;

        int wm = (w >> 1) * 64, wf = (w & 1) * 64;
        int lm = l & 15;

        f32x4 c1[4][4], c2[4][4];
#pragma unroll
        for (int mi = 0; mi < 4; ++mi)
#pragma unroll
            for (int fj = 0; fj < 4; ++fj) {
                c1[mi][fj] = (f32x4){0.f, 0.f, 0.f, 0.f};
                c2[mi][fj] = (f32x4){0.f, 0.f, 0.f, 0.f};
            }

        auto stage = [&](int buf, int k0) {
            __bf16* base = &smem[buf][0];
#pragma unroll
            for (int j = 0; j < 4; ++j)
                async16(aptr[j] + k0, base + w * 2048 + j * 512);
            async16(b1base + k0,               base + 16384 + w * 1024);
            async16(b1base + 8 * D_MODEL + k0, base + 16384 + w * 1024 + 512);
            async16(b2base + k0,               base + 24576 + w * 1024);
            async16(b2base + 8 * D_MODEL + k0, base + 24576 + w * 1024 + 512);
        };

        stage(0, 0);
        __syncthreads();
        const int NT = D_MODEL / 64;   // 16
        for (int t = 0; t < NT; ++t) {
            int cur = t & 1;
            if (t + 1 < NT) stage(cur ^ 1, (t + 1) * 64);
            const __bf16* sb = &smem[cur][0];
#pragma unroll
            for (int ks = 0; ks < 2; ++ks) {
                int sl = (((ks * 4 + (l >> 4)) ^ (l & 7)) << 3);   // read XOR = row&7
                bf16x8 a[4];
#pragma unroll
                for (int mi = 0; mi < 4; ++mi)
                    a[mi] = *reinterpret_cast<const bf16x8*>(sb + (wm + mi * 16 + lm) * 64 + sl);
#pragma unroll
                for (int fj = 0; fj < 4; ++fj) {
                    int frow = wf + fj * 16 + lm;
                    bf16x8 bv1 = *reinterpret_cast<const bf16x8*>(sb + 16384 + frow * 64 + sl);
                    bf16x8 bv2 = *reinterpret_cast<const bf16x8*>(sb + 24576 + frow * 64 + sl);
#pragma unroll
                    for (int mi = 0; mi < 4; ++mi) {
                        c1[mi][fj] = __builtin_amdgcn_mfma_f32_16x16x32_bf16(a[mi], bv1, c1[mi][fj], 0, 0, 0);
                        c2[mi][fj] = __builtin_amdgcn_mfma_f32_16x16x32_bf16(a[mi], bv2, c2[mi][fj], 0, 0, 0);
                    }
                }
            }
            __syncthreads();
        }

#pragma unroll
        for (int fj = 0; fj < 4; ++fj) {
            int f = fblk + wf + fj * 16 + lm;
            float b1v = b1[e * D_FF + f];
            float b2v = b2[e * D_FF + f];
#pragma unroll
            for (int mi = 0; mi < 4; ++mi)
#pragma unroll
                for (int r = 0; r < 4; ++r) {
                    int m = wm + mi * 16 + (l >> 4) * 4 + r;
                    float h1 = c1[mi][fj][r] + b1v;
                    float h2 = c2[mi][fj][r] + b2v;
                    float g = 0.5f * h1 * (1.f + erff(h1 * 0.70710678118654752f));
                    hidden[(size_t)(r0 + m) * D_FF + f] = (__bf16)(g * h2);
                }
        }
        __syncthreads();   // smem reuse below
    }

    // ---- W3 transpose tail: tiles {wgid + k*nwg} (bijective coverage) ----
    {
        int nwg = gridDim.x;
        float* smf = reinterpret_cast<float*>(&smem[0][0]);
        int sub = tid >> 8;
        float (*tb)[65] = reinterpret_cast<float (*)[65]>(smf + sub * 8520);
        int stid = tid & 255;
        for (int t0 = wgid; t0 < NW3T; t0 += 2 * nwg) {
            int t1 = t0 + nwg;
            if (t1 >= NW3T) t1 = t0;      // duplicate work: identical bytes, race-benign
            int tt = sub ? t1 : t0;
            int te = tt >> 9, rem = tt & 511;
            int kt_i = rem >> 4, nt_i = rem & 15;   // 32 ktiles x 16 ntiles
            transpose_tile_k128<false>(W3 + ((size_t)te << 22), W3t + ((size_t)te << 22),
                                       D_FF, D_MODEL, kt_i * 128, nt_i * 64, stid, tb);
            __syncthreads();
        }
    }
}

// ---------------- GEMM2: 128x128, BK=64, K=4096, po-store + XCD swizzle ----------------
__global__ __launch_bounds__(512, 4) void gemm2_mfma(
    const __bf16* __restrict__ hidden, const __bf16* __restrict__ W3t,
    const float* __restrict__ b3, const int* __restrict__ rbe,
    float* __restrict__ po, int nrb)
{
    int wgid = xcd_swizzle(blockIdx.x, gridDim.x);
    int rb = wgid % nrb;           // 128-row block
    int e = rbe[rb >> 1];
    if (e < 0) return;
    int dblk = (wgid / nrb) * 128;

    __shared__ __bf16 smem[2][16384];

    int tid = threadIdx.x, w = tid >> 6, l = tid & 63;
    int ss8 = (l & 7) ^ (l >> 3);
    int r0m = rb * 128;

    const __bf16* abase = hidden + (size_t)(r0m + w * 16 + (l >> 3)) * D_FF + ss8 * 8;
    const __bf16* bbase = W3t + ((size_t)e << 22)
        + (size_t)(dblk + w * 16 + (l >> 3)) * D_FF + ss8 * 8;

    int wm = (w >> 1) * 32, wn = (w & 1) * 64;
    int lm = l & 15;

    f32x4 c[2][4];
#pragma unroll
    for (int mi = 0; mi < 2; ++mi)
#pragma unroll
        for (int nj = 0; nj < 4; ++nj) c[mi][nj] = (f32x4){0.f, 0.f, 0.f, 0.f};

    auto stage = [&](int buf, int k0) {
        __bf16* base = &smem[buf][0];
        async16(abase + k0,              base + w * 1024 + l * 8);
        async16(abase + 8 * D_FF + k0,   base + w * 1024 + 512 + l * 8);
        async16(bbase + k0,              base + 8192 + w * 1024 + l * 8);
        async16(bbase + 8 * D_FF + k0,   base + 8192 + w * 1024 + 512 + l * 8);
    };

    stage(0, 0);
    __syncthreads();
    const int NT = D_FF / 64;   // 64
    for (int t = 0; t < NT; ++t) {
        int cur = t & 1;
        if (t + 1 < NT) stage(cur ^ 1, (t + 1) * 64);
        const __bf16* sb = &smem[cur][0];
#pragma unroll
        for (int ks = 0; ks < 2; ++ks) {
            int sl = (((ks * 4 + (l >> 4)) ^ (l & 7)) << 3);
            bf16x8 a[2];
#pragma unroll
            for (int mi = 0; mi < 2; ++mi)
                a[mi] = *reinterpret_cast<const bf16x8*>(sb + (wm + mi * 16 + lm) * 64 + sl);
#pragma unroll
            for (int nj = 0; nj < 4; ++nj) {
                bf16x8 bv = *reinterpret_cast<const bf16x8*>(sb + 8192 + (wn + nj * 16 + lm) * 64 + sl);
#pragma unroll
                for (int mi = 0; mi < 2; ++mi)
                    c[mi][nj] = __builtin_amdgcn_mfma_f32_16x16x32_bf16(a[mi], bv, c[mi][nj], 0, 0, 0);
            }
        }
        __syncthreads();
    }

#pragma unroll
    for (int nj = 0; nj < 4; ++nj) {
        int d = dblk + wn + nj * 16 + lm;
        float b3v = b3[e * D_MODEL + d];
#pragma unroll
        for (int mi = 0; mi < 2; ++mi)
#pragma unroll
            for (int r = 0; r < 4; ++r) {
                int m = wm + mi * 16 + (l >> 4) * 4 + r;
                po[(size_t)(r0m + m) * D_MODEL + d] = c[mi][nj][r] + b3v;
            }
    }
}

// ---------------- combine: out[t] = w0*po[r0] + w1*po[r1] ----------------
__global__ __launch_bounds__(256) void combine_kernel(
    const float* __restrict__ po, const float* __restrict__ topw,
    const int* __restrict__ pairRow, float* __restrict__ out)
{
    int t = blockIdx.x, tid = threadIdx.x;
    int d = tid * 4;
    float w0 = topw[t * 2], w1 = topw[t * 2 + 1];
    int r0 = pairRow[t * 2], r1 = pairRow[t * 2 + 1];
    float4 v0 = *reinterpret_cast<const float4*>(po + (size_t)r0 * D_MODEL + d);
    float4 v1 = *reinterpret_cast<const float4*>(po + (size_t)r1 * D_MODEL + d);
    float4 o;
    o.x = w0 * v0.x + w1 * v1.x;
    o.y = w0 * v0.y + w1 * v1.y;
    o.z = w0 * v0.z + w1 * v1.z;
    o.w = w0 * v0.w + w1 * v1.w;
    *reinterpret_cast<float4*>(out + (size_t)t * D_MODEL + d) = o;
}

extern "C" void kernel_launch(void* const* d_in, const int* in_sizes, int n_in,
                              void* d_out, int out_size, void* d_ws, size_t ws_size,
                              hipStream_t stream)
{
    const float* x  = (const float*)d_in[0];
    const float* Wg = (const float*)d_in[1];
    const float* bg = (const float*)d_in[2];
    const float* W1 = (const float*)d_in[3];
    const float* b1 = (const float*)d_in[4];
    const float* W2 = (const float*)d_in[5];
    const float* b2 = (const float*)d_in[6];
    const float* W3 = (const float*)d_in[7];
    const float* b3 = (const float*)d_in[8];
    float* out = (float*)d_out;

    int N = in_sizes[0] / D_MODEL;     // 2048
    int npairs = N * 2;
    int maxblk = npairs / MT + NE;     // 24
    int maxrows = maxblk * MT;         // 6144

    char* ws = (char*)d_ws;
    size_t off = 0;
    auto alloc = [&](size_t bytes) -> void* {
        void* p = ws + off;
        off = (off + bytes + 255) & ~(size_t)255;
        return p;
    };
    int*    topidx  = (int*)   alloc((size_t)npairs * 4);
    float*  topw    = (float*) alloc((size_t)npairs * 4);
    int*    pairTok = (int*)   alloc((size_t)maxrows * 4);
    float*  pairW   = (float*) alloc((size_t)maxrows * 4);
    int*    rbe     = (int*)   alloc((size_t)maxblk * 4);
    int*    pairRow = (int*)   alloc((size_t)npairs * 4);
    __bf16* Xb      = (__bf16*)alloc((size_t)N * D_MODEL * 2);
    __bf16* hidden  = (__bf16*)alloc((size_t)maxrows * D_FF * 2);
    __bf16* zpg     = (__bf16*)alloc(4096);
    const size_t WSZ = (size_t)NE * D_MODEL * D_FF * 2;   // 64 MB per matrix
    __bf16* W1t = (__bf16*)alloc(WSZ);
    __bf16* W2t = (__bf16*)alloc(WSZ);
    __bf16* W3t = (__bf16*)alloc(WSZ);
    float*  po  = (float*)W1t;   // overlay: W1t dead after gemm1 (25MB < 64MB)
    (void)ws_size; (void)n_in; (void)pairW;

    hipMemsetAsync(zpg, 0, 4096, stream);

    // router + T(W1) + T(W2) only — T(W3) rides under gemm1
    fused_pre<<<N + 2 * 4096, 256, 0, stream>>>(
        x, Wg, bg, topidx, topw, Xb, W1, W2, W1t, W2t, N);
    build_lists_kernel<<<1, 256, 0, stream>>>(topidx, topw, pairTok, pairW, rbe,
                                              pairRow, npairs, maxrows, maxblk);
    gemm1_mfma<<<maxblk * (D_FF / 128), 512, 0, stream>>>(
        Xb, W1t, W2t, b1, b2, pairTok, rbe, zpg, hidden, W3, W3t, maxblk);
    gemm2_mfma<<<(maxblk * 2) * (D_MODEL / 128), 512, 0, stream>>>(
        hidden, W3t, b3, rbe, po, maxblk * 2);
    combine_kernel<<<N, 256, 0, stream>>>(po, topw, pairRow, out);
}

// Round 18
// 284.370 us; speedup vs baseline: 1.6850x; 1.0956x over previous
//
#include <hip/hip_runtime.h>
#include <hip/hip_bf16.h>
#include <math.h>

#define D_MODEL 1024
#define D_FF    4096
#define NE      8
#define MT      256   // list alignment / gemm1 M tile
#define NW3T    4096  // W3 transpose tiles: 8e x 32kt x 16nt (128k x 64f)

typedef __bf16 bf16x8 __attribute__((ext_vector_type(8)));
typedef float  f32x4  __attribute__((ext_vector_type(4)));
typedef short  s16x8  __attribute__((ext_vector_type(8)));

__device__ __forceinline__ void async16(const void* g, void* l) {
    __builtin_amdgcn_global_load_lds(
        (__attribute__((address_space(1))) uint32_t*)g,
        (__attribute__((address_space(3))) uint32_t*)l, 16, 0, 0);
}

// bijective XCD chunking (m204): contiguous runs of nwg/8 blocks per XCD
__device__ __forceinline__ int xcd_swizzle(int lin, int nwg) {
    if ((nwg & 7) != 0) return lin;
    int q = nwg >> 3;
    return (lin & 7) * q + (lin >> 3);
}

// 128k x 64f transpose+cvt tile: src[K][N] f32 -> dst[N][K] bf16. (R9-verified)
// NT_LOAD only: sources are read-once (dead after) -> skip cache retention.
// Stores are ALWAYS plain: W*t is consumed by the NEXT kernel; R16/R17 A/B showed
// NT stores evict it from L3 and cost gemm1 ~+20us in read latency.
template <bool NT_LOAD>
__device__ __forceinline__ void transpose_tile_k128(
    const float* __restrict__ s, __bf16* __restrict__ d,
    int K, int N, int kt, int nt, int tid, float (*tile)[65])
{
    int tr = tid >> 4, tc = (tid & 15) * 4;
#pragma unroll
    for (int p = 0; p < 8; ++p) {
        const f32x4* sp = reinterpret_cast<const f32x4*>(
            s + (size_t)(kt + tr + p * 16) * N + nt + tc);
        f32x4 v = NT_LOAD ? __builtin_nontemporal_load(sp) : *sp;
        tile[tr + p * 16][tc + 0] = v.x;
        tile[tr + p * 16][tc + 1] = v.y;
        tile[tr + p * 16][tc + 2] = v.z;
        tile[tr + p * 16][tc + 3] = v.w;
    }
    __syncthreads();
    int kq = (tid & 15) * 8;
#pragma unroll
    for (int p = 0; p < 4; ++p) {
        int rr = (tid >> 4) + p * 16;   // f within tile
        bf16x8 pk;
#pragma unroll
        for (int i = 0; i < 8; ++i) pk[i] = (__bf16)tile[kq + i][rr];
        *reinterpret_cast<bf16x8*>(d + (size_t)(nt + rr) * K + kt + kq) = pk;
    }
}

// -------- fused: router (bid<nrouter) | T(W1) | T(W2)  (W3 rides under gemm1) --------
__global__ __launch_bounds__(256) void fused_pre(
    const float* __restrict__ x, const float* __restrict__ Wg,
    const float* __restrict__ bg, int* __restrict__ topidx,
    float* __restrict__ topw, __bf16* __restrict__ Xb,
    const float* __restrict__ W1, const float* __restrict__ W2,
    __bf16* __restrict__ W1t, __bf16* __restrict__ W2t, int nrouter)
{
    __shared__ float buf[128][65];
    int bid = blockIdx.x, tid = threadIdx.x;

    if (bid >= nrouter) {
        int tt = bid - nrouter;        // [0, 2*4096)
        const float* s = W1; __bf16* d = W1t;
        if (tt >= 4096) { s = W2; d = W2t; tt -= 4096; }
        int e = tt >> 9, rem = tt & 511;
        int kt_i = rem >> 6, nt_i = rem & 63;   // 8 ktiles x 64 ntiles
        transpose_tile_k128<true>(s + ((size_t)e << 22), d + ((size_t)e << 22),
                                  D_MODEL, D_FF, kt_i * 128, nt_i * 64, tid, buf);
        return;
    }

    int n = bid;
    const float* xr = x + (size_t)n * D_MODEL;
    int d0 = tid * 4;
    float4 xv = *reinterpret_cast<const float4*>(xr + d0);

    union { __bf16 h[4]; ushort4 u; } pk;
    pk.h[0] = (__bf16)xv.x; pk.h[1] = (__bf16)xv.y;
    pk.h[2] = (__bf16)xv.z; pk.h[3] = (__bf16)xv.w;
    *reinterpret_cast<ushort4*>(Xb + (size_t)n * D_MODEL + d0) = pk.u;

    float part[NE];
#pragma unroll
    for (int e = 0; e < NE; ++e) part[e] = 0.f;
    float xs[4] = {xv.x, xv.y, xv.z, xv.w};
#pragma unroll
    for (int j = 0; j < 4; ++j) {
        const float4* wr = reinterpret_cast<const float4*>(Wg + (size_t)(d0 + j) * NE);
        float4 w0 = wr[0], w1 = wr[1];
        part[0] += xs[j] * w0.x; part[1] += xs[j] * w0.y;
        part[2] += xs[j] * w0.z; part[3] += xs[j] * w0.w;
        part[4] += xs[j] * w1.x; part[5] += xs[j] * w1.y;
        part[6] += xs[j] * w1.z; part[7] += xs[j] * w1.w;
    }
#pragma unroll
    for (int off = 32; off > 0; off >>= 1) {
#pragma unroll
        for (int e = 0; e < NE; ++e) part[e] += __shfl_down(part[e], off);
    }
    float* sred = &buf[0][0];
    float* slog = &buf[1][0];
    int wave = tid >> 6, lane = tid & 63;
    if (lane == 0) {
#pragma unroll
        for (int e = 0; e < NE; ++e) sred[wave * NE + e] = part[e];
    }
    __syncthreads();
    if (tid < NE)
        slog[tid] = bg[tid] + sred[tid] + sred[NE + tid] + sred[2 * NE + tid] + sred[3 * NE + tid];
    __syncthreads();
    if (tid == 0) {
        float m0 = -1e30f, m1 = -1e30f; int i0 = 0, i1 = 0;
        for (int e = 0; e < NE; ++e) {
            float l = slog[e];
            if (l > m0)      { m1 = m0; i1 = i0; m0 = l; i0 = e; }
            else if (l > m1) { m1 = l;  i1 = e; }
        }
        float w1 = expf(m1 - m0);
        float s  = 1.f + w1;
        topidx[n * 2 + 0] = i0; topidx[n * 2 + 1] = i1;
        topw[n * 2 + 0] = 1.f / s; topw[n * 2 + 1] = w1 / s;
    }
}

// ---------------- build per-expert padded row lists (align 256) + pairRow ----------------
__global__ __launch_bounds__(256) void build_lists_kernel(
    const int* __restrict__ topidx, const float* __restrict__ topw,
    int* __restrict__ pairTok, float* __restrict__ pairW,
    int* __restrict__ rbe, int* __restrict__ pairRow,
    int npairs, int maxrows, int maxblk)
{
    __shared__ int cnt[NE], cur[NE], pof[NE];
    int tid = threadIdx.x;
    if (tid < NE) { cnt[tid] = 0; cur[tid] = 0; }
    for (int i = tid; i < maxrows; i += 256) pairTok[i] = -1;
    for (int i = tid; i < maxblk; i += 256) rbe[i] = -1;
    __syncthreads();
    for (int p = tid; p < npairs; p += 256) atomicAdd(&cnt[topidx[p]], 1);
    __syncthreads();
    if (tid == 0) {
        int off = 0;
        for (int e = 0; e < NE; ++e) { pof[e] = off; off += (cnt[e] + MT - 1) & ~(MT - 1); }
        for (int e = 0; e < NE; ++e) {
            int nb = (cnt[e] + MT - 1) / MT;
            for (int j = 0; j < nb; ++j) rbe[pof[e] / MT + j] = e;
        }
    }
    __syncthreads();
    for (int p = tid; p < npairs; p += 256) {
        int e = topidx[p];
        int pos = atomicAdd(&cur[e], 1);
        int r = pof[e] + pos;
        pairTok[r]  = p >> 1;
        pairW[r]    = topw[p];
        pairRow[p]  = r;
    }
}

// ---- GEMM1 (R13 body) + W3-transpose tail (NT loads, plain stores) ----
// R8 lesson: acc=128 regs, no min-waves launch_bounds.
__global__ __launch_bounds__(512) void gemm1_mfma(
    const __bf16* __restrict__ Xb, const __bf16* __restrict__ W1t,
    const __bf16* __restrict__ W2t, const float* __restrict__ b1,
    const float* __restrict__ b2, const int* __restrict__ pairTok,
    const int* __restrict__ rbe, const __bf16* __restrict__ zpg,
    __bf16* __restrict__ hidden,
    const float* __restrict__ W3, __bf16* __restrict__ W3t, int maxblk)
{
    __shared__ __bf16 smem[2][32768];
    int wgid = xcd_swizzle(blockIdx.x, gridDim.x);
    int b = wgid % maxblk;
    int e = rbe[b];
    int fblk = (wgid / maxblk) * 128;
    int tid = threadIdx.x, w = tid >> 6, l = tid & 63;

    if (e >= 0) {
        int srcslot = (l & 7) ^ (l >> 3);   // LDS[row][s] = src[row][s ^ (row&7)]
        int r0 = b * MT;

        const __bf16* aptr[4];
#pragma unroll
        for (int j = 0; j < 4; ++j) {
            int row = w * 32 + j * 8 + (l >> 3);
            int tok = pairTok[r0 + row];
            aptr[j] = (tok >= 0 ? Xb + (size_t)tok * D_MODEL : zpg) + srcslot * 8;
        }
        const __bf16* b1base = W1t + ((size_t)e << 22)
            + (size_t)(fblk + w * 16 + (l >> 3)) * D_MODEL + srcslot * 8;
        const __bf16* b2base = W2t + ((size_t)e << 22)
            + (size_t)(fblk + w * 16 + (l >> 3)) * D_MODEL + srcslot * 8;

        int wm = (w >> 1) * 64, wf = (w & 1) * 64;
        int lm = l & 15;

        f32x4 c1[4][4], c2[4][4];
#pragma unroll
        for (int mi = 0; mi < 4; ++mi)
#pragma unroll
            for (int fj = 0; fj < 4; ++fj) {
                c1[mi][fj] = (f32x4){0.f, 0.f, 0.f, 0.f};
                c2[mi][fj] = (f32x4){0.f, 0.f, 0.f, 0.f};
            }

        auto stage = [&](int buf, int k0) {
            __bf16* base = &smem[buf][0];
#pragma unroll
            for (int j = 0; j < 4; ++j)
                async16(aptr[j] + k0, base + w * 2048 + j * 512);
            async16(b1base + k0,               base + 16384 + w * 1024);
            async16(b1base + 8 * D_MODEL + k0, base + 16384 + w * 1024 + 512);
            async16(b2base + k0,               base + 24576 + w * 1024);
            async16(b2base + 8 * D_MODEL + k0, base + 24576 + w * 1024 + 512);
        };

        stage(0, 0);
        __syncthreads();
        const int NT = D_MODEL / 64;   // 16
        for (int t = 0; t < NT; ++t) {
            int cur = t & 1;
            if (t + 1 < NT) stage(cur ^ 1, (t + 1) * 64);
            const __bf16* sb = &smem[cur][0];
#pragma unroll
            for (int ks = 0; ks < 2; ++ks) {
                int sl = (((ks * 4 + (l >> 4)) ^ (l & 7)) << 3);   // read XOR = row&7
                bf16x8 a[4];
#pragma unroll
                for (int mi = 0; mi < 4; ++mi)
                    a[mi] = *reinterpret_cast<const bf16x8*>(sb + (wm + mi * 16 + lm) * 64 + sl);
#pragma unroll
                for (int fj = 0; fj < 4; ++fj) {
                    int frow = wf + fj * 16 + lm;
                    bf16x8 bv1 = *reinterpret_cast<const bf16x8*>(sb + 16384 + frow * 64 + sl);
                    bf16x8 bv2 = *reinterpret_cast<const bf16x8*>(sb + 24576 + frow * 64 + sl);
#pragma unroll
                    for (int mi = 0; mi < 4; ++mi) {
                        c1[mi][fj] = __builtin_amdgcn_mfma_f32_16x16x32_bf16(a[mi], bv1, c1[mi][fj], 0, 0, 0);
                        c2[mi][fj] = __builtin_amdgcn_mfma_f32_16x16x32_bf16(a[mi], bv2, c2[mi][fj], 0, 0, 0);
                    }
                }
            }
            __syncthreads();
        }

#pragma unroll
        for (int fj = 0; fj < 4; ++fj) {
            int f = fblk + wf + fj * 16 + lm;
            float b1v = b1[e * D_FF + f];
            float b2v = b2[e * D_FF + f];
#pragma unroll
            for (int mi = 0; mi < 4; ++mi)
#pragma unroll
                for (int r = 0; r < 4; ++r) {
                    int m = wm + mi * 16 + (l >> 4) * 4 + r;
                    float h1 = c1[mi][fj][r] + b1v;
                    float h2 = c2[mi][fj][r] + b2v;
                    float g = 0.5f * h1 * (1.f + erff(h1 * 0.70710678118654752f));
                    hidden[(size_t)(r0 + m) * D_FF + f] = (__bf16)(g * h2);
                }
        }
        __syncthreads();   // smem reuse below
    }

    // ---- W3 transpose tail: tiles {wgid + k*nwg} (bijective coverage) ----
    {
        int nwg = gridDim.x;
        float* smf = reinterpret_cast<float*>(&smem[0][0]);
        int sub = tid >> 8;
        float (*tb)[65] = reinterpret_cast<float (*)[65]>(smf + sub * 8520);
        int stid = tid & 255;
        for (int t0 = wgid; t0 < NW3T; t0 += 2 * nwg) {
            int t1 = t0 + nwg;
            if (t1 >= NW3T) t1 = t0;      // duplicate work: identical bytes, race-benign
            int tt = sub ? t1 : t0;
            int te = tt >> 9, rem = tt & 511;
            int kt_i = rem >> 4, nt_i = rem & 15;   // 32 ktiles x 16 ntiles
            transpose_tile_k128<true>(W3 + ((size_t)te << 22), W3t + ((size_t)te << 22),
                                      D_FF, D_MODEL, kt_i * 128, nt_i * 64, stid, tb);
            __syncthreads();
        }
    }
}

// ---------------- GEMM2: 128x128, BK=64, K=4096, po-store + XCD swizzle ----------------
__global__ __launch_bounds__(512, 4) void gemm2_mfma(
    const __bf16* __restrict__ hidden, const __bf16* __restrict__ W3t,
    const float* __restrict__ b3, const int* __restrict__ rbe,
    float* __restrict__ po, int nrb)
{
    int wgid = xcd_swizzle(blockIdx.x, gridDim.x);
    int rb = wgid % nrb;           // 128-row block
    int e = rbe[rb >> 1];
    if (e < 0) return;
    int dblk = (wgid / nrb) * 128;

    __shared__ __bf16 smem[2][16384];

    int tid = threadIdx.x, w = tid >> 6, l = tid & 63;
    int ss8 = (l & 7) ^ (l >> 3);
    int r0m = rb * 128;

    const __bf16* abase = hidden + (size_t)(r0m + w * 16 + (l >> 3)) * D_FF + ss8 * 8;
    const __bf16* bbase = W3t + ((size_t)e << 22)
        + (size_t)(dblk + w * 16 + (l >> 3)) * D_FF + ss8 * 8;

    int wm = (w >> 1) * 32, wn = (w & 1) * 64;
    int lm = l & 15;

    f32x4 c[2][4];
#pragma unroll
    for (int mi = 0; mi < 2; ++mi)
#pragma unroll
        for (int nj = 0; nj < 4; ++nj) c[mi][nj] = (f32x4){0.f, 0.f, 0.f, 0.f};

    auto stage = [&](int buf, int k0) {
        __bf16* base = &smem[buf][0];
        async16(abase + k0,              base + w * 1024 + l * 8);
        async16(abase + 8 * D_FF + k0,   base + w * 1024 + 512 + l * 8);
        async16(bbase + k0,              base + 8192 + w * 1024 + l * 8);
        async16(bbase + 8 * D_FF + k0,   base + 8192 + w * 1024 + 512 + l * 8);
    };

    stage(0, 0);
    __syncthreads();
    const int NT = D_FF / 64;   // 64
    for (int t = 0; t < NT; ++t) {
        int cur = t & 1;
        if (t + 1 < NT) stage(cur ^ 1, (t + 1) * 64);
        const __bf16* sb = &smem[cur][0];
#pragma unroll
        for (int ks = 0; ks < 2; ++ks) {
            int sl = (((ks * 4 + (l >> 4)) ^ (l & 7)) << 3);
            bf16x8 a[2];
#pragma unroll
            for (int mi = 0; mi < 2; ++mi)
                a[mi] = *reinterpret_cast<const bf16x8*>(sb + (wm + mi * 16 + lm) * 64 + sl);
#pragma unroll
            for (int nj = 0; nj < 4; ++nj) {
                bf16x8 bv = *reinterpret_cast<const bf16x8*>(sb + 8192 + (wn + nj * 16 + lm) * 64 + sl);
#pragma unroll
                for (int mi = 0; mi < 2; ++mi)
                    c[mi][nj] = __builtin_amdgcn_mfma_f32_16x16x32_bf16(a[mi], bv, c[mi][nj], 0, 0, 0);
            }
        }
        __syncthreads();
    }

#pragma unroll
    for (int nj = 0; nj < 4; ++nj) {
        int d = dblk + wn + nj * 16 + lm;
        float b3v = b3[e * D_MODEL + d];
#pragma unroll
        for (int mi = 0; mi < 2; ++mi)
#pragma unroll
            for (int r = 0; r < 4; ++r) {
                int m = wm + mi * 16 + (l >> 4) * 4 + r;
                po[(size_t)(r0m + m) * D_MODEL + d] = c[mi][nj][r] + b3v;
            }
    }
}

// ---------------- combine: out[t] = w0*po[r0] + w1*po[r1] ----------------
__global__ __launch_bounds__(256) void combine_kernel(
    const float* __restrict__ po, const float* __restrict__ topw,
    const int* __restrict__ pairRow, float* __restrict__ out)
{
    int t = blockIdx.x, tid = threadIdx.x;
    int d = tid * 4;
    float w0 = topw[t * 2], w1 = topw[t * 2 + 1];
    int r0 = pairRow[t * 2], r1 = pairRow[t * 2 + 1];
    float4 v0 = *reinterpret_cast<const float4*>(po + (size_t)r0 * D_MODEL + d);
    float4 v1 = *reinterpret_cast<const float4*>(po + (size_t)r1 * D_MODEL + d);
    float4 o;
    o.x = w0 * v0.x + w1 * v1.x;
    o.y = w0 * v0.y + w1 * v1.y;
    o.z = w0 * v0.z + w1 * v1.z;
    o.w = w0 * v0.w + w1 * v1.w;
    *reinterpret_cast<float4*>(out + (size_t)t * D_MODEL + d) = o;
}

extern "C" void kernel_launch(void* const* d_in, const int* in_sizes, int n_in,
                              void* d_out, int out_size, void* d_ws, size_t ws_size,
                              hipStream_t stream)
{
    const float* x  = (const float*)d_in[0];
    const float* Wg = (const float*)d_in[1];
    const float* bg = (const float*)d_in[2];
    const float* W1 = (const float*)d_in[3];
    const float* b1 = (const float*)d_in[4];
    const float* W2 = (const float*)d_in[5];
    const float* b2 = (const float*)d_in[6];
    const float* W3 = (const float*)d_in[7];
    const float* b3 = (const float*)d_in[8];
    float* out = (float*)d_out;

    int N = in_sizes[0] / D_MODEL;     // 2048
    int npairs = N * 2;
    int maxblk = npairs / MT + NE;     // 24
    int maxrows = maxblk * MT;         // 6144

    char* ws = (char*)d_ws;
    size_t off = 0;
    auto alloc = [&](size_t bytes) -> void* {
        void* p = ws + off;
        off = (off + bytes + 255) & ~(size_t)255;
        return p;
    };
    int*    topidx  = (int*)   alloc((size_t)npairs * 4);
    float*  topw    = (float*) alloc((size_t)npairs * 4);
    int*    pairTok = (int*)   alloc((size_t)maxrows * 4);
    float*  pairW   = (float*) alloc((size_t)maxrows * 4);
    int*    rbe     = (int*)   alloc((size_t)maxblk * 4);
    int*    pairRow = (int*)   alloc((size_t)npairs * 4);
    __bf16* Xb      = (__bf16*)alloc((size_t)N * D_MODEL * 2);
    __bf16* hidden  = (__bf16*)alloc((size_t)maxrows * D_FF * 2);
    __bf16* zpg     = (__bf16*)alloc(4096);
    const size_t WSZ = (size_t)NE * D_MODEL * D_FF * 2;   // 64 MB per matrix
    __bf16* W1t = (__bf16*)alloc(WSZ);
    __bf16* W2t = (__bf16*)alloc(WSZ);
    __bf16* W3t = (__bf16*)alloc(WSZ);
    float*  po  = (float*)W1t;   // overlay: W1t dead after gemm1 (25MB < 64MB)
    (void)ws_size; (void)n_in; (void)pairW;

    hipMemsetAsync(zpg, 0, 4096, stream);

    // router + T(W1) + T(W2) only — T(W3) rides under gemm1
    fused_pre<<<N + 2 * 4096, 256, 0, stream>>>(
        x, Wg, bg, topidx, topw, Xb, W1, W2, W1t, W2t, N);
    build_lists_kernel<<<1, 256, 0, stream>>>(topidx, topw, pairTok, pairW, rbe,
                                              pairRow, npairs, maxrows, maxblk);
    gemm1_mfma<<<maxblk * (D_FF / 128), 512, 0, stream>>>(
        Xb, W1t, W2t, b1, b2, pairTok, rbe, zpg, hidden, W3, W3t, maxblk);
    gemm2_mfma<<<(maxblk * 2) * (D_MODEL / 128), 512, 0, stream>>>(
        hidden, W3t, b3, rbe, po, maxblk * 2);
    combine_kernel<<<N, 256, 0, stream>>>(po, topw, pairRow, out);
}